// Round 1
// baseline (5817.499 us; speedup 1.0000x reference)
//
#include <hip/hip_runtime.h>
#include <math.h>

// ---- problem constants ----
#define BB    64
#define NN_   128
#define NH    6
#define DM    600     // d_model
#define RHID  300     // rnn hidden
#define DKH   100     // per-head dim
#define INDIM 360
#define G4    1200    // 4*RHID
#define WXROW 1206    // NH + 2*DM

// ---- workspace layout (float offsets). Peak = 27,689,920 floats = 110.8 MB ----
#define OFF_GIN    0ull
#define OFF_ASPECT 4915200ull
#define OFF_A      4960000ull
#define OFF_AW     4970000ull
#define OFF_ASC    5010000ull
#define OFF_W1SUM  5060000ull
#define OFF_W2SUM  5060600ull
#define OFF_SWX    5061200ull
#define OFF_SBX    5061208ull
#define OFF_SG1    5061212ull
#define OFF_SG2    5069404ull
#define ARENA      5080000ull
#define OFF_EMBS   (ARENA)                      // 2,949,120
#define OFF_XGF    (ARENA + 2949120ull)         // 9,830,400
#define OFF_XGB    (OFF_XGF + 9830400ull)       // 9,830,400 (peak)
#define OFF_Q      (ARENA)                      // 4,915,200 (over EMBS/XGF, dead)
#define OFF_K      (ARENA + 4915200ull)
#define OFF_ADJ    (ARENA + 9830400ull)         // 6,291,456
#define OFF_ADJS   (ARENA + 16121856ull)        // 1,048,576
#define OFF_WHS    (OFF_ADJS + 1048576ull)      // 1,048,576
#define OFF_AX     (ARENA)                      // over Q (dead)
#define OFF_G1     (ARENA + 4915200ull)         // over K (dead)
#define OFF_AX2    (ARENA + 9830400ull)         // over ADJ (dead)
#define OFF_G2     (OFF_ADJS)                   // over ADJS/WHS (dead by then)
#define OFF_HN     (ARENA)                      // over AX (dead)

__device__ __forceinline__ float sigm(float x){ return 1.f/(1.f+__expf(-x)); }
__device__ __forceinline__ float selu_f(float x){
  const float sc=1.0507009873554805f, al=1.6732632423543772f;
  return x>0.f ? sc*x : sc*al*(__expf(x)-1.f);
}

// ---------------- embedding concat ----------------
__global__ __launch_bounds__(384) void embed_k(
    const int* __restrict__ tok, const int* __restrict__ pos_ids, const int* __restrict__ post_ids,
    const float* __restrict__ emb_w, const float* __restrict__ pos_w, const float* __restrict__ post_w,
    float* __restrict__ embs)
{
  int bn = blockIdx.x, t = threadIdx.x;
  float v;
  if      (t < 300) v = emb_w [(size_t)tok     [bn]*300 + t];
  else if (t < 330) v = pos_w [(size_t)pos_ids [bn]*30  + (t-300)];
  else if (t < 360) v = post_w[(size_t)post_ids[bn]*30  + (t-330)];
  else return;
  embs[(size_t)bn*INDIM + t] = v;
}

// ---------------- Wx folded constants ----------------
__global__ __launch_bounds__(640) void consts_k(
    const float* __restrict__ Wx, const float* __restrict__ bx,
    float* __restrict__ w1sum, float* __restrict__ w2sum,
    float* __restrict__ swx, float* __restrict__ sbx)
{
  int t = threadIdx.x;
  if (t < DM){
    float s1=0.f, s2=0.f;
    for (int k=0;k<NH;++k){ s1 += Wx[k*WXROW + NH + t]; s2 += Wx[k*WXROW + NH + DM + t]; }
    w1sum[t]=s1; w2sum[t]=s2;
  } else if (t < DM+NH){
    int h=t-DM; float s=0.f;
    for (int k=0;k<NH;++k) s += Wx[k*WXROW + h];
    swx[h]=s;
  } else if (t == DM+NH){
    float s=0.f; for (int k=0;k<NH;++k) s += bx[k];
    sbx[0]=s;
  }
}

// ---------------- generic fp32 GEMM: C = act(A @ op(B) + bias) ----------------
// TRANSB=false: B is [N,K] row-major (weights, x@W.T).  TRANSB=true: B is [K,N] row-major.
// 128x128 tile, KT=16, 256 threads, 8x8 per thread.
template<bool TRANSB, int ACT>
__global__ __launch_bounds__(256) void gemm_k(
    const float* __restrict__ A, const float* __restrict__ Bm,
    const float* __restrict__ bias, float* __restrict__ C,
    int M, int Nn, int K, long long sA, long long sB, long long sC)
{
  __shared__ __align__(16) float As[16][132];
  __shared__ __align__(16) float Bs[16][132];
  const float* Ab = A  + (size_t)blockIdx.z * (size_t)sA;
  const float* Bb = Bm + (size_t)blockIdx.z * (size_t)sB;
  float*       Cb = C  + (size_t)blockIdx.z * (size_t)sC;
  const int m0 = blockIdx.y * 128, n0 = blockIdx.x * 128;
  const int lin = threadIdx.x;
  const int tx = lin & 15, ty = lin >> 4;
  float acc[8][8];
#pragma unroll
  for (int i=0;i<8;i++)
#pragma unroll
    for (int j=0;j<8;j++) acc[i][j]=0.f;

  for (int k0=0; k0<K; k0+=16) {
#pragma unroll
    for (int r=0;r<2;++r){
      int e = lin*2+r;                 // 0..511
      int row = e>>2, kq=(e&3)*4;
      float4 v = make_float4(0.f,0.f,0.f,0.f);
      int gm=m0+row, gk=k0+kq;
      if (gm<M && gk<K) v = *(const float4*)(Ab + (size_t)gm*K + gk);
      As[kq+0][row]=v.x; As[kq+1][row]=v.y; As[kq+2][row]=v.z; As[kq+3][row]=v.w;
    }
    if constexpr (!TRANSB) {
#pragma unroll
      for (int r=0;r<2;++r){
        int e = lin*2+r;
        int col = e>>2, kq=(e&3)*4;
        float4 v = make_float4(0.f,0.f,0.f,0.f);
        int gn=n0+col, gk=k0+kq;
        if (gn<Nn && gk<K) v = *(const float4*)(Bb + (size_t)gn*K + gk);
        Bs[kq+0][col]=v.x; Bs[kq+1][col]=v.y; Bs[kq+2][col]=v.z; Bs[kq+3][col]=v.w;
      }
    } else {
#pragma unroll
      for (int r=0;r<2;++r){
        int e = lin + 256*r;           // 0..511
        int kk = e>>5, nq = (e&31)*4;
        float4 v = make_float4(0.f,0.f,0.f,0.f);
        int gk=k0+kk, gn=n0+nq;
        if (gk<K && gn<Nn) v = *(const float4*)(Bb + (size_t)gk*Nn + gn);
        *(float4*)&Bs[kk][nq] = v;
      }
    }
    __syncthreads();
#pragma unroll
    for (int kk=0;kk<16;++kk){
      float a[8], bv[8];
      *(float4*)&a[0]  = *(const float4*)&As[kk][ty*8];
      *(float4*)&a[4]  = *(const float4*)&As[kk][ty*8+4];
      *(float4*)&bv[0] = *(const float4*)&Bs[kk][tx*8];
      *(float4*)&bv[4] = *(const float4*)&Bs[kk][tx*8+4];
#pragma unroll
      for (int i=0;i<8;i++)
#pragma unroll
        for (int j=0;j<8;j++) acc[i][j] = fmaf(a[i], bv[j], acc[i][j]);
    }
    __syncthreads();
  }

#pragma unroll
  for (int i=0;i<8;i++){
    int gm = m0 + ty*8 + i;
    if (gm>=M) continue;
#pragma unroll
    for (int j=0;j<8;j+=4){
      int gn = n0 + tx*8 + j;
      if (gn>=Nn) continue;            // Nn % 4 == 0 always here
      float t0=acc[i][j+0], t1=acc[i][j+1], t2=acc[i][j+2], t3=acc[i][j+3];
      if (bias){ t0+=bias[gn]; t1+=bias[gn+1]; t2+=bias[gn+2]; t3+=bias[gn+3]; }
      if (ACT==1){ t0=selu_f(t0); t1=selu_f(t1); t2=selu_f(t2); t3=selu_f(t3); }
      else if (ACT==2){ t0=fmaxf(t0,0.f); t1=fmaxf(t1,0.f); t2=fmaxf(t2,0.f); t3=fmaxf(t3,0.f); }
      float4 v; v.x=t0; v.y=t1; v.z=t2; v.w=t3;
      *(float4*)(Cb + (size_t)gm*Nn + gn) = v;
    }
  }
}

// ---------------- bidirectional LSTM recurrence ----------------
// grid (BB, 2): one block per (batch, direction). Whh streamed from L2 each step.
__global__ __launch_bounds__(320) void lstm_k(
    const float* __restrict__ xgf, const float* __restrict__ xgb,
    const float* __restrict__ whhf, const float* __restrict__ whhb,
    float* __restrict__ gin)
{
  const int b = blockIdx.x, dir = blockIdx.y;
  const float* xg  = dir ? xgb  : xgf;
  const float* Whh = dir ? whhb : whhf;
  __shared__ __align__(16) float h_lds[RHID];
  const int t = threadIdx.x;
  float c = 0.f;
  if (t < RHID) h_lds[t] = 0.f;
  __syncthreads();
  const float* w0 = Whh + (size_t)t*RHID;
  const float* w1 = Whh + (size_t)(RHID  +t)*RHID;
  const float* w2 = Whh + (size_t)(2*RHID+t)*RHID;
  const float* w3 = Whh + (size_t)(3*RHID+t)*RHID;
  for (int s=0;s<NN_;++s){
    int n = dir ? (NN_-1-s) : s;
    float a0=0.f,a1=0.f,a2=0.f,a3=0.f;
    if (t < RHID){
      const float* xr = xg + ((size_t)(b*NN_+n))*G4;
      a0 = xr[t]; a1 = xr[RHID+t]; a2 = xr[2*RHID+t]; a3 = xr[3*RHID+t];
#pragma unroll 5
      for (int kq=0; kq<RHID; kq+=4){
        float4 h4 = *(const float4*)&h_lds[kq];
        float4 x0 = *(const float4*)(w0+kq);
        float4 x1 = *(const float4*)(w1+kq);
        float4 x2 = *(const float4*)(w2+kq);
        float4 x3 = *(const float4*)(w3+kq);
        a0 += x0.x*h4.x + x0.y*h4.y + x0.z*h4.z + x0.w*h4.w;
        a1 += x1.x*h4.x + x1.y*h4.y + x1.z*h4.z + x1.w*h4.w;
        a2 += x2.x*h4.x + x2.y*h4.y + x2.z*h4.z + x2.w*h4.w;
        a3 += x3.x*h4.x + x3.y*h4.y + x3.z*h4.z + x3.w*h4.w;
      }
    }
    __syncthreads();   // all reads of h_lds done
    if (t < RHID){
      float ig = sigm(a0), fg = sigm(a1), gg = tanhf(a2), og = sigm(a3);
      c = fg*c + ig*gg;
      float h = og*tanhf(c);
      h_lds[t] = h;
      gin[((size_t)(b*NN_+n))*DM + dir*RHID + t] = h;
    }
    __syncthreads();   // writes visible before next step's reads
  }
}

// ---------------- masked mean over sequence -> aspect[B,DM] ----------------
__global__ __launch_bounds__(640) void aspect_k(
    const float* __restrict__ gin, const float* __restrict__ mask, float* __restrict__ aspect)
{
  int b = blockIdx.x, t = threadIdx.x;
  __shared__ float msk[NN_];
  __shared__ float wn;
  if (t < NN_) msk[t] = mask[b*NN_+t];
  __syncthreads();
  if (t==0){ float s=0.f; for (int n=0;n<NN_;++n) s+=msk[n]; wn=s; }
  __syncthreads();
  if (t < DM){
    float s=0.f;
    for (int n=0;n<NN_;++n) s += gin[((size_t)(b*NN_+n))*DM + t]*msk[n];
    aspect[b*DM+t] = s/wn;
  }
}

// ---------------- aw[b,h,e] = sum_d a[b,d] * weight_m[h,d,e] ----------------
__global__ __launch_bounds__(128) void aw_k(
    const float* __restrict__ a, const float* __restrict__ wm, float* __restrict__ aw)
{
  int b=blockIdx.x, h=blockIdx.y, e=threadIdx.x;
  if (e>=DKH) return;
  float s=0.f;
  for (int d=0; d<DKH; ++d) s += a[b*DKH+d]*wm[(h*DKH+d)*DKH+e];
  aw[(b*NH+h)*DKH+e]=s;
}

// ---------------- asc[b,h,m] = tanh(aw . k[b,h,m,:] + bias_m) ----------------
__global__ __launch_bounds__(128) void asc_k(
    const float* __restrict__ aw, const float* __restrict__ kp,
    const float* __restrict__ bias_m, float* __restrict__ asc)
{
  int b=blockIdx.x, h=blockIdx.y, m=threadIdx.x;
  __shared__ __align__(16) float awl[DKH];
  if (m<DKH) awl[m]=aw[(b*NH+h)*DKH+m];
  __syncthreads();
  const float* kr = kp + ((size_t)(b*NN_+m))*DM + h*DKH;
  const float4* a4=(const float4*)awl; const float4* k4=(const float4*)kr;
  float s=0.f;
#pragma unroll
  for (int e=0;e<DKH/4;e++){ float4 x=a4[e], y=k4[e]; s += x.x*y.x+x.y*y.y+x.z*y.z+x.w*y.w; }
  asc[(b*NH+h)*NN_+m] = tanhf(s + bias_m[0]);
}

// ---------------- scores + mask + short + softmax -> adj[B,H,N,N] ----------------
__global__ __launch_bounds__(128) void attn_k(
    const float* __restrict__ q, const float* __restrict__ kp,
    const float* __restrict__ asc, const float* __restrict__ shortm,
    const int* __restrict__ tok, float* __restrict__ adj)
{
  int n=blockIdx.x, h=blockIdx.y, b=blockIdx.z, m=threadIdx.x;
  __shared__ __align__(16) float qrow[DKH];
  __shared__ float red[NN_];
  if (m < DKH) qrow[m] = q[((size_t)(b*NN_+n))*DM + h*DKH + m];
  __syncthreads();
  const float* kr = kp + ((size_t)(b*NN_+m))*DM + h*DKH;
  const float4* q4=(const float4*)qrow; const float4* k4=(const float4*)kr;
  float s=0.f;
#pragma unroll
  for (int e=0;e<DKH/4;e++){ float4 x=q4[e], y=k4[e]; s += x.x*y.x+x.y*y.y+x.z*y.z+x.w*y.w; }
  s = s*0.1f + asc[(b*NH+h)*NN_+m];              // /sqrt(100) = *0.1
  if (tok[b*NN_+m]==0) s = -1e9f;                // where(src, s, -1e9)
  s += shortm[((size_t)(b*NN_+n))*NN_+m];        // short[B,1,N,N] broadcast over h
  red[m]=s; __syncthreads();
  for (int o=64;o;o>>=1){ if (m<o) red[m]=fmaxf(red[m],red[m+o]); __syncthreads(); }
  float mx = red[0]; __syncthreads();
  float e = __expf(s-mx);
  red[m]=e; __syncthreads();
  for (int o=64;o;o>>=1){ if (m<o) red[m]+=red[m+o]; __syncthreads(); }
  adj[(((size_t)b*NH+h)*NN_+n)*NN_+m] = e/red[0];
}

// ---------------- adjsum = sum_h adj / H; whs = sum_h adj*swx[h] / H ----------------
__global__ __launch_bounds__(256) void adjsum_k(
    const float* __restrict__ adj, const float* __restrict__ swx,
    float* __restrict__ adjs, float* __restrict__ whs)
{
  int idx = blockIdx.x*256 + threadIdx.x;        // < B*N*N = 1,048,576
  int b = idx >> 14, rem = idx & 16383;
  float s=0.f, w=0.f;
  for (int h=0;h<NH;++h){
    float v = adj[(((size_t)b*NH+h)<<14) + rem];
    s += v; w += v*swx[h];
  }
  adjs[idx] = s*(1.f/NH);
  whs [idx] = w*(1.f/NH);
}

// ---------------- sg1[b,j]=g1.w1sum  sg2[b,j]=g1.w2sum ----------------
__global__ __launch_bounds__(128) void sg_k(
    const float* __restrict__ g1, const float* __restrict__ w1sum, const float* __restrict__ w2sum,
    float* __restrict__ sg1, float* __restrict__ sg2)
{
  int row = blockIdx.x*128 + threadIdx.x;        // 0..8191
  const float* gr = g1 + (size_t)row*DM;
  float s1=0.f,s2=0.f;
  for (int d=0;d<DM;++d){ float g=gr[d]; s1+=g*w1sum[d]; s2+=g*w2sum[d]; }
  sg1[row]=s1; sg2[row]=s2;
}

// ---------------- adjsum2[b,i,j] = whs + (sg1[b,j]+sg2[b,i]+sbx)/H ----------------
__global__ __launch_bounds__(256) void adjsum2_k(
    const float* __restrict__ whs, const float* __restrict__ sg1, const float* __restrict__ sg2,
    const float* __restrict__ sbx, float* __restrict__ adjs)
{
  int idx = blockIdx.x*256 + threadIdx.x;
  int b = idx >> 14, rem = idx & 16383;
  int i = rem >> 7, j = rem & 127;
  adjs[idx] = whs[idx] + (sg1[b*NN_+j] + sg2[b*NN_+i] + sbx[0])*(1.f/NH);
}

// ---------------- pooled mean + logits ----------------
__global__ __launch_bounds__(320) void pooled_k(
    const float* __restrict__ hn, const float* __restrict__ mask,
    const float* __restrict__ Wc, const float* __restrict__ bc, float* __restrict__ out)
{
  int b=blockIdx.x, t=threadIdx.x;
  __shared__ float msk[NN_];
  __shared__ float pl[RHID];
  __shared__ float wn;
  if (t<NN_) msk[t]=mask[b*NN_+t];
  __syncthreads();
  if (t==0){ float s=0.f; for (int n=0;n<NN_;++n) s+=msk[n]; wn=s; }
  __syncthreads();
  if (t<RHID){
    float s=0.f;
    for (int n=0;n<NN_;++n) s += hn[((size_t)(b*NN_+n))*RHID+t]*msk[n];
    pl[t]=s/wn;
  }
  __syncthreads();
  if (t<3){
    float s=bc[t];
    for (int d=0;d<RHID;++d) s += pl[d]*Wc[t*RHID+d];
    out[b*3+t]=s;
  }
}

extern "C" void kernel_launch(void* const* d_in, const int* in_sizes, int n_in,
                              void* d_out, int out_size, void* d_ws, size_t ws_size,
                              hipStream_t stream)
{
  (void)in_sizes; (void)n_in; (void)out_size; (void)ws_size;
  const int*   tok      = (const int*)  d_in[0];
  const int*   pos_ids  = (const int*)  d_in[2];
  const int*   post_ids = (const int*)  d_in[5];
  const float* mask     = (const float*)d_in[6];
  const float* shortm   = (const float*)d_in[8];
  const float* emb_w    = (const float*)d_in[9];
  const float* pos_w    = (const float*)d_in[10];
  const float* post_w   = (const float*)d_in[11];
  const float* Wih_f    = (const float*)d_in[12];
  const float* Whh_f    = (const float*)d_in[13];
  const float* b_f      = (const float*)d_in[14];
  const float* Wih_b    = (const float*)d_in[15];
  const float* Whh_b    = (const float*)d_in[16];
  const float* b_b      = (const float*)d_in[17];
  const float* Wq       = (const float*)d_in[18];
  const float* bq       = (const float*)d_in[19];
  const float* Wk       = (const float*)d_in[20];
  const float* bk       = (const float*)d_in[21];
  const float* Wd       = (const float*)d_in[22];
  const float* bd       = (const float*)d_in[23];
  const float* weight_m = (const float*)d_in[24];
  const float* bias_m   = (const float*)d_in[25];
  const float* Ww       = (const float*)d_in[26];
  const float* bw       = (const float*)d_in[27];
  const float* Wx       = (const float*)d_in[28];
  const float* bx       = (const float*)d_in[29];
  const float* Wxx      = (const float*)d_in[30];
  const float* bxx      = (const float*)d_in[31];
  const float* Wc       = (const float*)d_in[32];
  const float* bc       = (const float*)d_in[33];

  float* ws  = (float*)d_ws;
  float* out = (float*)d_out;

  float* gin    = ws + OFF_GIN;
  float* aspect = ws + OFF_ASPECT;
  float* abuf   = ws + OFF_A;
  float* awb    = ws + OFF_AW;
  float* ascb   = ws + OFF_ASC;
  float* w1sum  = ws + OFF_W1SUM;
  float* w2sum  = ws + OFF_W2SUM;
  float* swx    = ws + OFF_SWX;
  float* sbx    = ws + OFF_SBX;
  float* sg1    = ws + OFF_SG1;
  float* sg2    = ws + OFF_SG2;
  float* embs   = ws + OFF_EMBS;
  float* xgf    = ws + OFF_XGF;
  float* xgb    = ws + OFF_XGB;
  float* qb     = ws + OFF_Q;
  float* kb     = ws + OFF_K;
  float* adjb   = ws + OFF_ADJ;
  float* adjs   = ws + OFF_ADJS;
  float* whs    = ws + OFF_WHS;
  float* axb    = ws + OFF_AX;
  float* g1b    = ws + OFF_G1;
  float* ax2b   = ws + OFF_AX2;
  float* g2b    = ws + OFF_G2;
  float* hnb    = ws + OFF_HN;

  // 1. embeddings + folded Wx constants
  embed_k<<<dim3(BB*NN_),384,0,stream>>>(tok,pos_ids,post_ids,emb_w,pos_w,post_w,embs);
  consts_k<<<1,640,0,stream>>>(Wx,bx,w1sum,w2sum,swx,sbx);
  // 2. LSTM input projections (both directions, natural time order)
  gemm_k<false,0><<<dim3(10,64,1),256,0,stream>>>(embs,Wih_f,b_f,xgf, BB*NN_,G4,INDIM, 0,0,0);
  gemm_k<false,0><<<dim3(10,64,1),256,0,stream>>>(embs,Wih_b,b_b,xgb, BB*NN_,G4,INDIM, 0,0,0);
  // 3. recurrence -> g_in[B,N,600] (fwd cols 0:300, bwd cols 300:600)
  lstm_k<<<dim3(BB,2),320,0,stream>>>(xgf,xgb,Whh_f,Whh_b,gin);
  // 4. aspect mean, Q/K projections, aspect-bias path
  aspect_k<<<BB,640,0,stream>>>(gin,mask,aspect);
  gemm_k<false,0><<<dim3(5,64,1),256,0,stream>>>(gin,Wq,bq,qb, BB*NN_,DM,DM, 0,0,0);
  gemm_k<false,0><<<dim3(5,64,1),256,0,stream>>>(gin,Wk,bk,kb, BB*NN_,DM,DM, 0,0,0);
  gemm_k<false,0><<<dim3(1,1,1),256,0,stream>>>(aspect,Wd,bd,abuf, BB,DKH,DM, 0,0,0);
  aw_k <<<dim3(BB,NH),128,0,stream>>>(abuf,weight_m,awb);
  asc_k<<<dim3(BB,NH),128,0,stream>>>(awb,kb,bias_m,ascb);
  // 5. scores + softmax
  attn_k<<<dim3(NN_,NH,BB),128,0,stream>>>(qb,kb,ascb,shortm,tok,adjb);
  // 6. GCN layer 1 (head-sum folded; 1/H folded into adjsum)
  adjsum_k<<<4096,256,0,stream>>>(adjb,swx,adjs,whs);
  gemm_k<true,0><<<dim3(5,1,64),256,0,stream>>>(adjs,gin,nullptr,axb, NN_,DM,NN_, 16384,76800,76800);
  gemm_k<false,1><<<dim3(5,64,1),256,0,stream>>>(axb,Ww,bw,g1b, BB*NN_,DM,DM, 0,0,0);
  // 7. layer-2 adjacency collapsed to [B,N,N] (edge tensor never materialized)
  sg_k<<<64,128,0,stream>>>(g1b,w1sum,w2sum,sg1,sg2);
  adjsum2_k<<<4096,256,0,stream>>>(whs,sg1,sg2,sbx,adjs);
  // 8. GCN layer 2 (final edge update is dead code -> skipped)
  gemm_k<true,0><<<dim3(5,1,64),256,0,stream>>>(adjs,g1b,nullptr,ax2b, NN_,DM,NN_, 16384,76800,76800);
  gemm_k<false,1><<<dim3(5,64,1),256,0,stream>>>(ax2b,Ww,bw,g2b, BB*NN_,DM,DM, 0,0,0);
  // 9. head: hnode relu, masked mean, logits
  gemm_k<false,2><<<dim3(3,64,1),256,0,stream>>>(g2b,Wxx,bxx,hnb, BB*NN_,RHID,DM, 0,0,0);
  pooled_k<<<BB,320,0,stream>>>(hnb,mask,Wc,bc,out);
}

// Round 2
// 3728.381 us; speedup vs baseline: 1.5603x; 1.5603x over previous
//
#include <hip/hip_runtime.h>
#include <math.h>

// ---- problem constants ----
#define BB    64
#define NN_   128
#define NH    6
#define DM    600     // d_model
#define RHID  300     // rnn hidden
#define DKH   100     // per-head dim
#define INDIM 360
#define G4    1200    // 4*RHID
#define WXROW 1206    // NH + 2*DM

// ---- workspace layout (float offsets). Peak = 27,689,920 floats = 110.8 MB ----
#define OFF_GIN    0ull
#define OFF_ASPECT 4915200ull
#define OFF_A      4960000ull
#define OFF_AW     4970000ull
#define OFF_ASC    5010000ull
#define OFF_W1SUM  5060000ull
#define OFF_W2SUM  5060600ull
#define OFF_SWX    5061200ull
#define OFF_SBX    5061208ull
#define OFF_SG1    5061212ull
#define OFF_SG2    5069404ull
#define ARENA      5080000ull
#define OFF_EMBS   (ARENA)                      // 2,949,120 (dead after xg GEMMs)
#define OFF_WTF    (ARENA)                      // 360,000 (over embs, after xg GEMMs)
#define OFF_WTB    (ARENA + 360000ull)          // 360,000
#define OFF_XGF    (ARENA + 2949120ull)         // 9,830,400
#define OFF_XGB    (OFF_XGF + 9830400ull)       // 9,830,400 (peak)
#define OFF_Q      (ARENA)                      // 4,915,200 (over EMBS/WT, dead)
#define OFF_K      (ARENA + 4915200ull)
#define OFF_ADJ    (ARENA + 9830400ull)         // 6,291,456
#define OFF_ADJS   (ARENA + 16121856ull)        // 1,048,576
#define OFF_WHS    (OFF_ADJS + 1048576ull)      // 1,048,576
#define OFF_AX     (ARENA)                      // over Q (dead)
#define OFF_G1     (ARENA + 4915200ull)         // over K (dead)
#define OFF_AX2    (ARENA + 9830400ull)         // over ADJ (dead)
#define OFF_G2     (OFF_ADJS)                   // over ADJS/WHS (dead by then)
#define OFF_HN     (ARENA)                      // over AX (dead)

__device__ __forceinline__ float sigm(float x){ return 1.f/(1.f+__expf(-x)); }
__device__ __forceinline__ float selu_f(float x){
  const float sc=1.0507009873554805f, al=1.6732632423543772f;
  return x>0.f ? sc*x : sc*al*(__expf(x)-1.f);
}

// ---------------- embedding concat ----------------
__global__ __launch_bounds__(384) void embed_k(
    const int* __restrict__ tok, const int* __restrict__ pos_ids, const int* __restrict__ post_ids,
    const float* __restrict__ emb_w, const float* __restrict__ pos_w, const float* __restrict__ post_w,
    float* __restrict__ embs)
{
  int bn = blockIdx.x, t = threadIdx.x;
  float v;
  if      (t < 300) v = emb_w [(size_t)tok     [bn]*300 + t];
  else if (t < 330) v = pos_w [(size_t)pos_ids [bn]*30  + (t-300)];
  else if (t < 360) v = post_w[(size_t)post_ids[bn]*30  + (t-330)];
  else return;
  embs[(size_t)bn*INDIM + t] = v;
}

// ---------------- Wx folded constants ----------------
__global__ __launch_bounds__(640) void consts_k(
    const float* __restrict__ Wx, const float* __restrict__ bx,
    float* __restrict__ w1sum, float* __restrict__ w2sum,
    float* __restrict__ swx, float* __restrict__ sbx)
{
  int t = threadIdx.x;
  if (t < DM){
    float s1=0.f, s2=0.f;
    for (int k=0;k<NH;++k){ s1 += Wx[k*WXROW + NH + t]; s2 += Wx[k*WXROW + NH + DM + t]; }
    w1sum[t]=s1; w2sum[t]=s2;
  } else if (t < DM+NH){
    int h=t-DM; float s=0.f;
    for (int k=0;k<NH;++k) s += Wx[k*WXROW + h];
    swx[h]=s;
  } else if (t == DM+NH){
    float s=0.f; for (int k=0;k<NH;++k) s += bx[k];
    sbx[0]=s;
  }
}

// ---------------- Whh transpose/pack: WT[k][u][gate] = Whh[gate*300+u][k] ----------------
__global__ __launch_bounds__(256) void whht_k(const float* __restrict__ Whh, float* __restrict__ WT)
{
  int idx = blockIdx.x*256 + threadIdx.x;       // < 360,000
  if (idx >= RHID*G4) return;
  int k = idx / G4, r = idx - k*G4;
  int u = r >> 2, g = r & 3;
  WT[idx] = Whh[((size_t)(g*RHID+u))*RHID + k];
}

// ---------------- generic fp32 GEMM: C = act(A @ op(B) + bias) ----------------
template<bool TRANSB, int ACT>
__global__ __launch_bounds__(256) void gemm_k(
    const float* __restrict__ A, const float* __restrict__ Bm,
    const float* __restrict__ bias, float* __restrict__ C,
    int M, int Nn, int K, long long sA, long long sB, long long sC)
{
  __shared__ __align__(16) float As[16][132];
  __shared__ __align__(16) float Bs[16][132];
  const float* Ab = A  + (size_t)blockIdx.z * (size_t)sA;
  const float* Bb = Bm + (size_t)blockIdx.z * (size_t)sB;
  float*       Cb = C  + (size_t)blockIdx.z * (size_t)sC;
  const int m0 = blockIdx.y * 128, n0 = blockIdx.x * 128;
  const int lin = threadIdx.x;
  const int tx = lin & 15, ty = lin >> 4;
  float acc[8][8];
#pragma unroll
  for (int i=0;i<8;i++)
#pragma unroll
    for (int j=0;j<8;j++) acc[i][j]=0.f;

  for (int k0=0; k0<K; k0+=16) {
#pragma unroll
    for (int r=0;r<2;++r){
      int e = lin*2+r;                 // 0..511
      int row = e>>2, kq=(e&3)*4;
      float4 v = make_float4(0.f,0.f,0.f,0.f);
      int gm=m0+row, gk=k0+kq;
      if (gm<M && gk<K) v = *(const float4*)(Ab + (size_t)gm*K + gk);
      As[kq+0][row]=v.x; As[kq+1][row]=v.y; As[kq+2][row]=v.z; As[kq+3][row]=v.w;
    }
    if constexpr (!TRANSB) {
#pragma unroll
      for (int r=0;r<2;++r){
        int e = lin*2+r;
        int col = e>>2, kq=(e&3)*4;
        float4 v = make_float4(0.f,0.f,0.f,0.f);
        int gn=n0+col, gk=k0+kq;
        if (gn<Nn && gk<K) v = *(const float4*)(Bb + (size_t)gn*K + gk);
        Bs[kq+0][col]=v.x; Bs[kq+1][col]=v.y; Bs[kq+2][col]=v.z; Bs[kq+3][col]=v.w;
      }
    } else {
#pragma unroll
      for (int r=0;r<2;++r){
        int e = lin + 256*r;           // 0..511
        int kk = e>>5, nq = (e&31)*4;
        float4 v = make_float4(0.f,0.f,0.f,0.f);
        int gk=k0+kk, gn=n0+nq;
        if (gk<K && gn<Nn) v = *(const float4*)(Bb + (size_t)gk*Nn + gn);
        *(float4*)&Bs[kk][nq] = v;
      }
    }
    __syncthreads();
#pragma unroll
    for (int kk=0;kk<16;++kk){
      float a[8], bv[8];
      *(float4*)&a[0]  = *(const float4*)&As[kk][ty*8];
      *(float4*)&a[4]  = *(const float4*)&As[kk][ty*8+4];
      *(float4*)&bv[0] = *(const float4*)&Bs[kk][tx*8];
      *(float4*)&bv[4] = *(const float4*)&Bs[kk][tx*8+4];
#pragma unroll
      for (int i=0;i<8;i++)
#pragma unroll
        for (int j=0;j<8;j++) acc[i][j] = fmaf(a[i], bv[j], acc[i][j]);
    }
    __syncthreads();
  }

#pragma unroll
  for (int i=0;i<8;i++){
    int gm = m0 + ty*8 + i;
    if (gm>=M) continue;
#pragma unroll
    for (int j=0;j<8;j+=4){
      int gn = n0 + tx*8 + j;
      if (gn>=Nn) continue;            // Nn % 4 == 0 always here
      float t0=acc[i][j+0], t1=acc[i][j+1], t2=acc[i][j+2], t3=acc[i][j+3];
      if (bias){ t0+=bias[gn]; t1+=bias[gn+1]; t2+=bias[gn+2]; t3+=bias[gn+3]; }
      if (ACT==1){ t0=selu_f(t0); t1=selu_f(t1); t2=selu_f(t2); t3=selu_f(t3); }
      else if (ACT==2){ t0=fmaxf(t0,0.f); t1=fmaxf(t1,0.f); t2=fmaxf(t2,0.f); t3=fmaxf(t3,0.f); }
      float4 v; v.x=t0; v.y=t1; v.z=t2; v.w=t3;
      *(float4*)(Cb + (size_t)gm*Nn + gn) = v;
    }
  }
}

// ---------------- bidirectional LSTM recurrence, coalesced transposed weights ----------------
// grid (BB/2, 2): one block per (batch-pair, direction). Thread u owns hidden unit u
// for BOTH batches: per k, one float4 = Whh^T gates {i,f,g,o} of unit u (lane-consecutive
// 16B -> fully coalesced), FMA'd into both batches' gate accumulators (weight reuse x2).
__global__ __launch_bounds__(320) void lstm2_k(
    const float* __restrict__ xgf, const float* __restrict__ xgb,
    const float* __restrict__ wtf, const float* __restrict__ wtb,
    float* __restrict__ gin)
{
  const int bp = blockIdx.x, dir = blockIdx.y;
  const int b0 = bp*2, b1 = b0+1;
  const float* xg = dir ? xgb : xgf;
  const float* WT = dir ? wtb : wtf;
  __shared__ __align__(16) float h0[RHID];
  __shared__ __align__(16) float h1[RHID];
  const int u = threadIdx.x;
  float c0 = 0.f, c1 = 0.f;
  if (u < RHID){ h0[u]=0.f; h1[u]=0.f; }
  __syncthreads();
  const float* wrow = WT + (size_t)u*4;
  for (int s=0;s<NN_;++s){
    int n = dir ? (NN_-1-s) : s;
    float A0=0.f,A1=0.f,A2=0.f,A3=0.f;   // gates i,f,g,o batch b0
    float B0=0.f,B1=0.f,B2=0.f,B3=0.f;   // batch b1
    if (u < RHID){
      const float* x0 = xg + ((size_t)(b0*NN_+n))*G4;
      const float* x1 = xg + ((size_t)(b1*NN_+n))*G4;
      A0 = x0[u]; A1 = x0[RHID+u]; A2 = x0[2*RHID+u]; A3 = x0[3*RHID+u];
      B0 = x1[u]; B1 = x1[RHID+u]; B2 = x1[2*RHID+u]; B3 = x1[3*RHID+u];
#pragma unroll 4
      for (int k=0; k<RHID; k+=4){
        float4 ha = *(const float4*)&h0[k];         // LDS broadcast
        float4 hb = *(const float4*)&h1[k];
        float4 w0 = *(const float4*)(wrow + (size_t)(k  )*G4);
        float4 w1 = *(const float4*)(wrow + (size_t)(k+1)*G4);
        float4 w2 = *(const float4*)(wrow + (size_t)(k+2)*G4);
        float4 w3 = *(const float4*)(wrow + (size_t)(k+3)*G4);
        A0 += w0.x*ha.x + w1.x*ha.y + w2.x*ha.z + w3.x*ha.w;
        A1 += w0.y*ha.x + w1.y*ha.y + w2.y*ha.z + w3.y*ha.w;
        A2 += w0.z*ha.x + w1.z*ha.y + w2.z*ha.z + w3.z*ha.w;
        A3 += w0.w*ha.x + w1.w*ha.y + w2.w*ha.z + w3.w*ha.w;
        B0 += w0.x*hb.x + w1.x*hb.y + w2.x*hb.z + w3.x*hb.w;
        B1 += w0.y*hb.x + w1.y*hb.y + w2.y*hb.z + w3.y*hb.w;
        B2 += w0.z*hb.x + w1.z*hb.y + w2.z*hb.z + w3.z*hb.w;
        B3 += w0.w*hb.x + w1.w*hb.y + w2.w*hb.z + w3.w*hb.w;
      }
    }
    __syncthreads();   // all reads of h done
    if (u < RHID){
      float ig = sigm(A0), fg = sigm(A1), gg = tanhf(A2), og = sigm(A3);
      c0 = fg*c0 + ig*gg;
      float hh0 = og*tanhf(c0);
      h0[u] = hh0;
      gin[((size_t)(b0*NN_+n))*DM + dir*RHID + u] = hh0;
      ig = sigm(B0); fg = sigm(B1); gg = tanhf(B2); og = sigm(B3);
      c1 = fg*c1 + ig*gg;
      float hh1 = og*tanhf(c1);
      h1[u] = hh1;
      gin[((size_t)(b1*NN_+n))*DM + dir*RHID + u] = hh1;
    }
    __syncthreads();   // writes visible before next step's reads
  }
}

// ---------------- masked mean over sequence -> aspect[B,DM] ----------------
__global__ __launch_bounds__(640) void aspect_k(
    const float* __restrict__ gin, const float* __restrict__ mask, float* __restrict__ aspect)
{
  int b = blockIdx.x, t = threadIdx.x;
  __shared__ float msk[NN_];
  __shared__ float wn;
  if (t < NN_) msk[t] = mask[b*NN_+t];
  __syncthreads();
  if (t==0){ float s=0.f; for (int n=0;n<NN_;++n) s+=msk[n]; wn=s; }
  __syncthreads();
  if (t < DM){
    float s=0.f;
    for (int n=0;n<NN_;++n) s += gin[((size_t)(b*NN_+n))*DM + t]*msk[n];
    aspect[b*DM+t] = s/wn;
  }
}

// ---------------- aw[b,h,e] = sum_d a[b,d] * weight_m[h,d,e] ----------------
__global__ __launch_bounds__(128) void aw_k(
    const float* __restrict__ a, const float* __restrict__ wm, float* __restrict__ aw)
{
  int b=blockIdx.x, h=blockIdx.y, e=threadIdx.x;
  if (e>=DKH) return;
  float s=0.f;
  for (int d=0; d<DKH; ++d) s += a[b*DKH+d]*wm[(h*DKH+d)*DKH+e];
  aw[(b*NH+h)*DKH+e]=s;
}

// ---------------- asc[b,h,m] = tanh(aw . k[b,h,m,:] + bias_m) ----------------
__global__ __launch_bounds__(128) void asc_k(
    const float* __restrict__ aw, const float* __restrict__ kp,
    const float* __restrict__ bias_m, float* __restrict__ asc)
{
  int b=blockIdx.x, h=blockIdx.y, m=threadIdx.x;
  __shared__ __align__(16) float awl[DKH];
  if (m<DKH) awl[m]=aw[(b*NH+h)*DKH+m];
  __syncthreads();
  const float* kr = kp + ((size_t)(b*NN_+m))*DM + h*DKH;
  const float4* a4=(const float4*)awl; const float4* k4=(const float4*)kr;
  float s=0.f;
#pragma unroll
  for (int e=0;e<DKH/4;e++){ float4 x=a4[e], y=k4[e]; s += x.x*y.x+x.y*y.y+x.z*y.z+x.w*y.w; }
  asc[(b*NH+h)*NN_+m] = tanhf(s + bias_m[0]);
}

// ---------------- scores + mask + short + softmax -> adj[B,H,N,N] ----------------
__global__ __launch_bounds__(128) void attn_k(
    const float* __restrict__ q, const float* __restrict__ kp,
    const float* __restrict__ asc, const float* __restrict__ shortm,
    const int* __restrict__ tok, float* __restrict__ adj)
{
  int n=blockIdx.x, h=blockIdx.y, b=blockIdx.z, m=threadIdx.x;
  __shared__ __align__(16) float qrow[DKH];
  __shared__ float red[NN_];
  if (m < DKH) qrow[m] = q[((size_t)(b*NN_+n))*DM + h*DKH + m];
  __syncthreads();
  const float* kr = kp + ((size_t)(b*NN_+m))*DM + h*DKH;
  const float4* q4=(const float4*)qrow; const float4* k4=(const float4*)kr;
  float s=0.f;
#pragma unroll
  for (int e=0;e<DKH/4;e++){ float4 x=q4[e], y=k4[e]; s += x.x*y.x+x.y*y.y+x.z*y.z+x.w*y.w; }
  s = s*0.1f + asc[(b*NH+h)*NN_+m];              // /sqrt(100) = *0.1
  if (tok[b*NN_+m]==0) s = -1e9f;                // where(src, s, -1e9)
  s += shortm[((size_t)(b*NN_+n))*NN_+m];        // short[B,1,N,N] broadcast over h
  red[m]=s; __syncthreads();
  for (int o=64;o;o>>=1){ if (m<o) red[m]=fmaxf(red[m],red[m+o]); __syncthreads(); }
  float mx = red[0]; __syncthreads();
  float e = __expf(s-mx);
  red[m]=e; __syncthreads();
  for (int o=64;o;o>>=1){ if (m<o) red[m]+=red[m+o]; __syncthreads(); }
  adj[(((size_t)b*NH+h)*NN_+n)*NN_+m] = e/red[0];
}

// ---------------- adjsum = sum_h adj / H; whs = sum_h adj*swx[h] / H ----------------
__global__ __launch_bounds__(256) void adjsum_k(
    const float* __restrict__ adj, const float* __restrict__ swx,
    float* __restrict__ adjs, float* __restrict__ whs)
{
  int idx = blockIdx.x*256 + threadIdx.x;        // < B*N*N = 1,048,576
  int b = idx >> 14, rem = idx & 16383;
  float s=0.f, w=0.f;
  for (int h=0;h<NH;++h){
    float v = adj[(((size_t)b*NH+h)<<14) + rem];
    s += v; w += v*swx[h];
  }
  adjs[idx] = s*(1.f/NH);
  whs [idx] = w*(1.f/NH);
}

// ---------------- sg1[b,j]=g1.w1sum  sg2[b,j]=g1.w2sum ----------------
__global__ __launch_bounds__(128) void sg_k(
    const float* __restrict__ g1, const float* __restrict__ w1sum, const float* __restrict__ w2sum,
    float* __restrict__ sg1, float* __restrict__ sg2)
{
  int row = blockIdx.x*128 + threadIdx.x;        // 0..8191
  const float* gr = g1 + (size_t)row*DM;
  float s1=0.f,s2=0.f;
  for (int d=0;d<DM;++d){ float g=gr[d]; s1+=g*w1sum[d]; s2+=g*w2sum[d]; }
  sg1[row]=s1; sg2[row]=s2;
}

// ---------------- adjsum2[b,i,j] = whs + (sg1[b,j]+sg2[b,i]+sbx)/H ----------------
__global__ __launch_bounds__(256) void adjsum2_k(
    const float* __restrict__ whs, const float* __restrict__ sg1, const float* __restrict__ sg2,
    const float* __restrict__ sbx, float* __restrict__ adjs)
{
  int idx = blockIdx.x*256 + threadIdx.x;
  int b = idx >> 14, rem = idx & 16383;
  int i = rem >> 7, j = rem & 127;
  adjs[idx] = whs[idx] + (sg1[b*NN_+j] + sg2[b*NN_+i] + sbx[0])*(1.f/NH);
}

// ---------------- pooled mean + logits ----------------
__global__ __launch_bounds__(320) void pooled_k(
    const float* __restrict__ hn, const float* __restrict__ mask,
    const float* __restrict__ Wc, const float* __restrict__ bc, float* __restrict__ out)
{
  int b=blockIdx.x, t=threadIdx.x;
  __shared__ float msk[NN_];
  __shared__ float pl[RHID];
  __shared__ float wn;
  if (t<NN_) msk[t]=mask[b*NN_+t];
  __syncthreads();
  if (t==0){ float s=0.f; for (int n=0;n<NN_;++n) s+=msk[n]; wn=s; }
  __syncthreads();
  if (t<RHID){
    float s=0.f;
    for (int n=0;n<NN_;++n) s += hn[((size_t)(b*NN_+n))*RHID+t]*msk[n];
    pl[t]=s/wn;
  }
  __syncthreads();
  if (t<3){
    float s=bc[t];
    for (int d=0;d<RHID;++d) s += pl[d]*Wc[t*RHID+d];
    out[b*3+t]=s;
  }
}

extern "C" void kernel_launch(void* const* d_in, const int* in_sizes, int n_in,
                              void* d_out, int out_size, void* d_ws, size_t ws_size,
                              hipStream_t stream)
{
  (void)in_sizes; (void)n_in; (void)out_size; (void)ws_size;
  const int*   tok      = (const int*)  d_in[0];
  const int*   pos_ids  = (const int*)  d_in[2];
  const int*   post_ids = (const int*)  d_in[5];
  const float* mask     = (const float*)d_in[6];
  const float* shortm   = (const float*)d_in[8];
  const float* emb_w    = (const float*)d_in[9];
  const float* pos_w    = (const float*)d_in[10];
  const float* post_w   = (const float*)d_in[11];
  const float* Wih_f    = (const float*)d_in[12];
  const float* Whh_f    = (const float*)d_in[13];
  const float* b_f      = (const float*)d_in[14];
  const float* Wih_b    = (const float*)d_in[15];
  const float* Whh_b    = (const float*)d_in[16];
  const float* b_b      = (const float*)d_in[17];
  const float* Wq       = (const float*)d_in[18];
  const float* bq       = (const float*)d_in[19];
  const float* Wk       = (const float*)d_in[20];
  const float* bk       = (const float*)d_in[21];
  const float* Wd       = (const float*)d_in[22];
  const float* bd       = (const float*)d_in[23];
  const float* weight_m = (const float*)d_in[24];
  const float* bias_m   = (const float*)d_in[25];
  const float* Ww       = (const float*)d_in[26];
  const float* bw       = (const float*)d_in[27];
  const float* Wx       = (const float*)d_in[28];
  const float* bx       = (const float*)d_in[29];
  const float* Wxx      = (const float*)d_in[30];
  const float* bxx      = (const float*)d_in[31];
  const float* Wc       = (const float*)d_in[32];
  const float* bc       = (const float*)d_in[33];

  float* ws  = (float*)d_ws;
  float* out = (float*)d_out;

  float* gin    = ws + OFF_GIN;
  float* aspect = ws + OFF_ASPECT;
  float* abuf   = ws + OFF_A;
  float* awb    = ws + OFF_AW;
  float* ascb   = ws + OFF_ASC;
  float* w1sum  = ws + OFF_W1SUM;
  float* w2sum  = ws + OFF_W2SUM;
  float* swx    = ws + OFF_SWX;
  float* sbx    = ws + OFF_SBX;
  float* sg1    = ws + OFF_SG1;
  float* sg2    = ws + OFF_SG2;
  float* embs   = ws + OFF_EMBS;
  float* wtf    = ws + OFF_WTF;
  float* wtb    = ws + OFF_WTB;
  float* xgf    = ws + OFF_XGF;
  float* xgb    = ws + OFF_XGB;
  float* qb     = ws + OFF_Q;
  float* kb     = ws + OFF_K;
  float* adjb   = ws + OFF_ADJ;
  float* adjs   = ws + OFF_ADJS;
  float* whs    = ws + OFF_WHS;
  float* axb    = ws + OFF_AX;
  float* g1b    = ws + OFF_G1;
  float* ax2b   = ws + OFF_AX2;
  float* g2b    = ws + OFF_G2;
  float* hnb    = ws + OFF_HN;

  // 1. embeddings + folded Wx constants
  embed_k<<<dim3(BB*NN_),384,0,stream>>>(tok,pos_ids,post_ids,emb_w,pos_w,post_w,embs);
  consts_k<<<1,640,0,stream>>>(Wx,bx,w1sum,w2sum,swx,sbx);
  // 2. LSTM input projections (both directions, natural time order)
  gemm_k<false,0><<<dim3(10,64,1),256,0,stream>>>(embs,Wih_f,b_f,xgf, BB*NN_,G4,INDIM, 0,0,0);
  gemm_k<false,0><<<dim3(10,64,1),256,0,stream>>>(embs,Wih_b,b_b,xgb, BB*NN_,G4,INDIM, 0,0,0);
  // 2b. pack/transpose Whh -> WT[k][u][gate] (into dead embs region; embs consumed above)
  whht_k<<<dim3((RHID*G4+255)/256),256,0,stream>>>(Whh_f,wtf);
  whht_k<<<dim3((RHID*G4+255)/256),256,0,stream>>>(Whh_b,wtb);
  // 3. recurrence -> g_in[B,N,600] (fwd cols 0:300, bwd cols 300:600)
  lstm2_k<<<dim3(BB/2,2),320,0,stream>>>(xgf,xgb,wtf,wtb,gin);
  // 4. aspect mean, Q/K projections, aspect-bias path
  aspect_k<<<BB,640,0,stream>>>(gin,mask,aspect);
  gemm_k<false,0><<<dim3(5,64,1),256,0,stream>>>(gin,Wq,bq,qb, BB*NN_,DM,DM, 0,0,0);
  gemm_k<false,0><<<dim3(5,64,1),256,0,stream>>>(gin,Wk,bk,kb, BB*NN_,DM,DM, 0,0,0);
  gemm_k<false,0><<<dim3(1,1,1),256,0,stream>>>(aspect,Wd,bd,abuf, BB,DKH,DM, 0,0,0);
  aw_k <<<dim3(BB,NH),128,0,stream>>>(abuf,weight_m,awb);
  asc_k<<<dim3(BB,NH),128,0,stream>>>(awb,kb,bias_m,ascb);
  // 5. scores + softmax
  attn_k<<<dim3(NN_,NH,BB),128,0,stream>>>(qb,kb,ascb,shortm,tok,adjb);
  // 6. GCN layer 1 (head-sum folded; 1/H folded into adjsum)
  adjsum_k<<<4096,256,0,stream>>>(adjb,swx,adjs,whs);
  gemm_k<true,0><<<dim3(5,1,64),256,0,stream>>>(adjs,gin,nullptr,axb, NN_,DM,NN_, 16384,76800,76800);
  gemm_k<false,1><<<dim3(5,64,1),256,0,stream>>>(axb,Ww,bw,g1b, BB*NN_,DM,DM, 0,0,0);
  // 7. layer-2 adjacency collapsed to [B,N,N] (edge tensor never materialized)
  sg_k<<<64,128,0,stream>>>(g1b,w1sum,w2sum,sg1,sg2);
  adjsum2_k<<<4096,256,0,stream>>>(whs,sg1,sg2,sbx,adjs);
  // 8. GCN layer 2 (final edge update is dead code -> skipped)
  gemm_k<true,0><<<dim3(5,1,64),256,0,stream>>>(adjs,g1b,nullptr,ax2b, NN_,DM,NN_, 16384,76800,76800);
  gemm_k<false,1><<<dim3(5,64,1),256,0,stream>>>(ax2b,Ww,bw,g2b, BB*NN_,DM,DM, 0,0,0);
  // 9. head: hnode relu, masked mean, logits
  gemm_k<false,2><<<dim3(3,64,1),256,0,stream>>>(g2b,Wxx,bxx,hnb, BB*NN_,RHID,DM, 0,0,0);
  pooled_k<<<BB,320,0,stream>>>(hnb,mask,Wc,bc,out);
}

// Round 3
// 3038.605 us; speedup vs baseline: 1.9145x; 1.2270x over previous
//
#include <hip/hip_runtime.h>
#include <math.h>

// ---- problem constants ----
#define BB    64
#define NN_   128
#define NH    6
#define DM    600     // d_model
#define RHID  300     // rnn hidden
#define DKH   100     // per-head dim
#define INDIM 360
#define G4    1200    // 4*RHID
#define WXROW 1206    // NH + 2*DM

// ---- LSTM cluster config ----
#define S_CL  25      // blocks per direction (cluster width)
#define NSU   12      // units per block
#define NSR   48      // packed gate-rows per block (= NSU*4)
#define KPAD  320     // K=300 padded to mult of 32

// ---- workspace layout (float offsets). Peak ~ 25.2M floats = 100.7 MB ----
#define OFF_GIN    0ull                         // 4,915,200 (written by lstm)
#define OFF_EMBS   0ull                         // embs aliases gin (dead before lstm writes)
#define OFF_WIHPF  2949120ull                   // 432,000 (dead before lstm)
#define OFF_WIHPB  3381120ull                   // 432,000
#define OFF_BPF    3813120ull                   // 1,200
#define OFF_BPB    3814320ull                   // 1,200 -> end 3,815,520 < 4,915,200 OK
#define OFF_ASPECT 4915200ull
#define OFF_A      4960000ull
#define OFF_AW     4970000ull
#define OFF_ASC    5010000ull
#define OFF_W1SUM  5060000ull
#define OFF_W2SUM  5060600ull
#define OFF_SWX    5061200ull
#define OFF_SBX    5061208ull
#define OFF_SG1    5061212ull
#define OFF_SG2    5069404ull
#define ARENA      5080000ull
#define OFF_XGF    (ARENA)                      // 9,830,400 fp32
#define OFF_XGB    (ARENA + 9830400ull)         // 9,830,400 fp32
#define OFF_WTB    (ARENA + 19660800ull)        // 768,000 bf16 = 384,000 f-slots
#define OFF_HBUF   (ARENA + 20044800ull)        // 81,920 bf16 = 40,960 f-slots
#define OFF_CTR    (ARENA + 20085760ull)        // ints (few)
// later phases reuse dead space (same offsets as R2):
#define OFF_Q      (ARENA)                      // over XGF (dead)
#define OFF_K      (ARENA + 4915200ull)
#define OFF_ADJ    (ARENA + 9830400ull)         // over XGB (dead)
#define OFF_ADJS   (ARENA + 16121856ull)
#define OFF_WHS    (OFF_ADJS + 1048576ull)
#define OFF_AX     (ARENA)
#define OFF_G1     (ARENA + 4915200ull)
#define OFF_AX2    (ARENA + 9830400ull)
#define OFF_G2     (OFF_ADJS)                   // over ADJS/WHS/WTB (dead by then)
#define OFF_HN     (ARENA)

typedef __bf16 bf16x8 __attribute__((ext_vector_type(8)));
typedef float  f32x4  __attribute__((ext_vector_type(4)));

__device__ __forceinline__ float sigm(float x){ return 1.f/(1.f+__expf(-x)); }
__device__ __forceinline__ float selu_f(float x){
  const float sc=1.0507009873554805f, al=1.6732632423543772f;
  return x>0.f ? sc*x : sc*al*(__expf(x)-1.f);
}

// ---------------- embedding concat ----------------
__global__ __launch_bounds__(384) void embed_k(
    const int* __restrict__ tok, const int* __restrict__ pos_ids, const int* __restrict__ post_ids,
    const float* __restrict__ emb_w, const float* __restrict__ pos_w, const float* __restrict__ post_w,
    float* __restrict__ embs)
{
  int bn = blockIdx.x, t = threadIdx.x;
  float v;
  if      (t < 300) v = emb_w [(size_t)tok     [bn]*300 + t];
  else if (t < 330) v = pos_w [(size_t)pos_ids [bn]*30  + (t-300)];
  else if (t < 360) v = post_w[(size_t)post_ids[bn]*30  + (t-330)];
  else return;
  embs[(size_t)bn*INDIM + t] = v;
}

// ---------------- Wx folded constants ----------------
__global__ __launch_bounds__(640) void consts_k(
    const float* __restrict__ Wx, const float* __restrict__ bx,
    float* __restrict__ w1sum, float* __restrict__ w2sum,
    float* __restrict__ swx, float* __restrict__ sbx)
{
  int t = threadIdx.x;
  if (t < DM){
    float s1=0.f, s2=0.f;
    for (int k=0;k<NH;++k){ s1 += Wx[k*WXROW + NH + t]; s2 += Wx[k*WXROW + NH + DM + t]; }
    w1sum[t]=s1; w2sum[t]=s2;
  } else if (t < DM+NH){
    int h=t-DM; float s=0.f;
    for (int k=0;k<NH;++k) s += Wx[k*WXROW + h];
    swx[h]=s;
  } else if (t == DM+NH){
    float s=0.f; for (int k=0;k<NH;++k) s += bx[k];
    sbx[0]=s;
  }
}

// ---------------- pack Wih rows into gate-interleaved order p=4u+g ----------------
__global__ __launch_bounds__(256) void wihp_k(
    const float* __restrict__ Wih, const float* __restrict__ b,
    float* __restrict__ outW, float* __restrict__ outB)
{
  int idx = blockIdx.x*256 + threadIdx.x;
  if (idx < G4*INDIM){
    int p = idx / INDIM, k = idx - p*INDIM;
    outW[idx] = Wih[((size_t)((p&3)*RHID + (p>>2)))*INDIM + k];
  } else if (idx < G4*INDIM + G4){
    int p = idx - G4*INDIM;
    outB[p] = b[(p&3)*RHID + (p>>2)];
  }
}

// ---------------- pack Whh -> bf16 [p=4u+g][KPAD] ----------------
__global__ __launch_bounds__(256) void whhp_k(
    const float* __restrict__ Whh, __bf16* __restrict__ outW)
{
  int idx = blockIdx.x*256 + threadIdx.x;
  if (idx >= G4*KPAD) return;
  int p = idx / KPAD, k = idx - p*KPAD;
  outW[idx] = (k < RHID) ? (__bf16)Whh[((size_t)((p&3)*RHID + (p>>2)))*RHID + k] : (__bf16)0.f;
}

// ---------------- zero hbuf + cluster counters ----------------
__global__ __launch_bounds__(256) void init_k(float* __restrict__ z)
{
  int idx = blockIdx.x*256 + threadIdx.x;
  if (idx < 40964) z[idx] = 0.f;     // 40,960 f-slots of hbuf + counters
}

// ---------------- generic fp32 GEMM: C = act(A @ op(B) + bias) ----------------
template<bool TRANSB, int ACT>
__global__ __launch_bounds__(256) void gemm_k(
    const float* __restrict__ A, const float* __restrict__ Bm,
    const float* __restrict__ bias, float* __restrict__ C,
    int M, int Nn, int K, long long sA, long long sB, long long sC)
{
  __shared__ __align__(16) float As[16][132];
  __shared__ __align__(16) float Bs[16][132];
  const float* Ab = A  + (size_t)blockIdx.z * (size_t)sA;
  const float* Bb = Bm + (size_t)blockIdx.z * (size_t)sB;
  float*       Cb = C  + (size_t)blockIdx.z * (size_t)sC;
  const int m0 = blockIdx.y * 128, n0 = blockIdx.x * 128;
  const int lin = threadIdx.x;
  const int tx = lin & 15, ty = lin >> 4;
  float acc[8][8];
#pragma unroll
  for (int i=0;i<8;i++)
#pragma unroll
    for (int j=0;j<8;j++) acc[i][j]=0.f;

  for (int k0=0; k0<K; k0+=16) {
#pragma unroll
    for (int r=0;r<2;++r){
      int e = lin*2+r;
      int row = e>>2, kq=(e&3)*4;
      float4 v = make_float4(0.f,0.f,0.f,0.f);
      int gm=m0+row, gk=k0+kq;
      if (gm<M && gk<K) v = *(const float4*)(Ab + (size_t)gm*K + gk);
      As[kq+0][row]=v.x; As[kq+1][row]=v.y; As[kq+2][row]=v.z; As[kq+3][row]=v.w;
    }
    if constexpr (!TRANSB) {
#pragma unroll
      for (int r=0;r<2;++r){
        int e = lin*2+r;
        int col = e>>2, kq=(e&3)*4;
        float4 v = make_float4(0.f,0.f,0.f,0.f);
        int gn=n0+col, gk=k0+kq;
        if (gn<Nn && gk<K) v = *(const float4*)(Bb + (size_t)gn*K + gk);
        Bs[kq+0][col]=v.x; Bs[kq+1][col]=v.y; Bs[kq+2][col]=v.z; Bs[kq+3][col]=v.w;
      }
    } else {
#pragma unroll
      for (int r=0;r<2;++r){
        int e = lin + 256*r;
        int kk = e>>5, nq = (e&31)*4;
        float4 v = make_float4(0.f,0.f,0.f,0.f);
        int gk=k0+kk, gn=n0+nq;
        if (gk<K && gn<Nn) v = *(const float4*)(Bb + (size_t)gk*Nn + gn);
        *(float4*)&Bs[kk][nq] = v;
      }
    }
    __syncthreads();
#pragma unroll
    for (int kk=0;kk<16;++kk){
      float a[8], bv[8];
      *(float4*)&a[0]  = *(const float4*)&As[kk][ty*8];
      *(float4*)&a[4]  = *(const float4*)&As[kk][ty*8+4];
      *(float4*)&bv[0] = *(const float4*)&Bs[kk][tx*8];
      *(float4*)&bv[4] = *(const float4*)&Bs[kk][tx*8+4];
#pragma unroll
      for (int i=0;i<8;i++)
#pragma unroll
        for (int j=0;j<8;j++) acc[i][j] = fmaf(a[i], bv[j], acc[i][j]);
    }
    __syncthreads();
  }

#pragma unroll
  for (int i=0;i<8;i++){
    int gm = m0 + ty*8 + i;
    if (gm>=M) continue;
#pragma unroll
    for (int j=0;j<8;j+=4){
      int gn = n0 + tx*8 + j;
      if (gn>=Nn) continue;
      float t0=acc[i][j+0], t1=acc[i][j+1], t2=acc[i][j+2], t3=acc[i][j+3];
      if (bias){ t0+=bias[gn]; t1+=bias[gn+1]; t2+=bias[gn+2]; t3+=bias[gn+3]; }
      if (ACT==1){ t0=selu_f(t0); t1=selu_f(t1); t2=selu_f(t2); t3=selu_f(t3); }
      else if (ACT==2){ t0=fmaxf(t0,0.f); t1=fmaxf(t1,0.f); t2=fmaxf(t2,0.f); t3=fmaxf(t3,0.f); }
      float4 v; v.x=t0; v.y=t1; v.z=t2; v.w=t3;
      *(float4*)(Cb + (size_t)gm*Nn + gn) = v;
    }
  }
}

// ---------------- cooperative-cluster MFMA LSTM ----------------
// 50 blocks (2 dirs x 25 slices), 256 threads. Weights VGPR-resident as B-fragments.
// Per step: h(s-1)[64,320]bf16 -> MFMA -> gates -> c/h update -> publish h(s) -> 25-wide barrier.
__global__ __launch_bounds__(256, 1) void lstm_mfma_k(
    const float* __restrict__ xgf, const float* __restrict__ xgb,
    const __bf16* __restrict__ wtb,          // [2][1200][KPAD]
    __bf16* hbuf,                            // [2 dir][2 pp][64][KPAD]
    int* ctr,                                // [2]
    float* __restrict__ gin)
{
  const int blk = blockIdx.x;
  const int dir = blk / S_CL, sl = blk - dir*S_CL;
  const int tid = threadIdx.x, lane = tid & 63, wave = tid >> 6;
  const int p0 = sl * NSR;
  const float* xg = dir ? xgb : xgf;
  const __bf16* W = wtb + (size_t)dir * G4 * KPAD;
  __bf16* hb = hbuf + (size_t)dir * 2 * BB * KPAD;
  int* c_ctr = ctr + dir;

  __shared__ __align__(16) float accS[NSR][68];   // [n_local][m] padded

  const int fn = lane & 15;            // A: batch-row / B: gate-row / D: col index
  const int fk = (lane >> 4) * 8;      // k sub-slice
  const int m0 = wave * 16;

  // ---- preload weight B-fragments into VGPRs (once) ----
  bf16x8 Bf[3][10];
#pragma unroll
  for (int nt = 0; nt < 3; ++nt)
#pragma unroll
    for (int kt = 0; kt < 10; ++kt)
      Bf[nt][kt] = *(const bf16x8*)(W + (size_t)(p0 + nt*16 + fn)*KPAD + kt*32 + fk);

  // ---- per-thread epilogue items: 768 = 64 b x 12 u -> 3 per thread ----
  int ib[3], iu[3]; float cst[3];
#pragma unroll
  for (int j = 0; j < 3; ++j){
    int item = tid + 256*j;
    iu[j] = item % NSU; ib[j] = item / NSU;
    cst[j] = 0.f;
  }

  for (int s = 0; s < NN_; ++s){
    const int n_t = dir ? (NN_-1-s) : s;
    const __bf16* hbr = hb + ((s+1)&1) * (BB*KPAD);   // h(s-1)
    __bf16*       hbw = hb + ( s   &1) * (BB*KPAD);   // h(s)

    // A fragments: rows = 16 batches of this wave's M-tile
    bf16x8 Af[10];
#pragma unroll
    for (int kt = 0; kt < 10; ++kt)
      Af[kt] = *(const bf16x8*)(hbr + (size_t)(m0 + fn)*KPAD + kt*32 + fk);

    f32x4 acc[3] = { {0.f,0.f,0.f,0.f}, {0.f,0.f,0.f,0.f}, {0.f,0.f,0.f,0.f} };
#pragma unroll
    for (int kt = 0; kt < 10; ++kt)
#pragma unroll
      for (int nt = 0; nt < 3; ++nt)
        acc[nt] = __builtin_amdgcn_mfma_f32_16x16x32_bf16(Af[kt], Bf[nt][kt], acc[nt], 0, 0, 0);

    // D -> LDS: accS[n_local][m];  D row m = m0 + (lane>>4)*4 + reg, col n = fn
#pragma unroll
    for (int nt = 0; nt < 3; ++nt)
      *(f32x4*)&accS[nt*16 + fn][m0 + (lane>>4)*4] = acc[nt];
    __syncthreads();

    // epilogue: gates -> c,h
#pragma unroll
    for (int j = 0; j < 3; ++j){
      int u = iu[j], b = ib[j];
      const float* xr = xg + ((size_t)(b*NN_ + n_t))*G4 + p0 + u*4;
      float4 x4 = *(const float4*)xr;
      float p_i = accS[u*4+0][b] + x4.x;
      float p_f = accS[u*4+1][b] + x4.y;
      float p_g = accS[u*4+2][b] + x4.z;
      float p_o = accS[u*4+3][b] + x4.w;
      float ig = sigm(p_i), fg = sigm(p_f), gg = tanhf(p_g), og = sigm(p_o);
      float c = fg*cst[j] + ig*gg; cst[j] = c;
      float h = og * tanhf(c);
      int u_glob = sl*NSU + u;
      hbw[(size_t)b*KPAD + u_glob] = (__bf16)h;
      gin[((size_t)(b*NN_ + n_t))*DM + dir*RHID + u_glob] = h;
    }
    __threadfence();
    __syncthreads();
    if (tid == 0){
      __hip_atomic_fetch_add(c_ctr, 1, __ATOMIC_RELEASE, __HIP_MEMORY_SCOPE_AGENT);
      const int target = S_CL * (s+1);
      while (__hip_atomic_load(c_ctr, __ATOMIC_ACQUIRE, __HIP_MEMORY_SCOPE_AGENT) < target)
        __builtin_amdgcn_s_sleep(2);
    }
    __syncthreads();
  }
}

// ---------------- masked mean over sequence -> aspect[B,DM] ----------------
__global__ __launch_bounds__(640) void aspect_k(
    const float* __restrict__ gin, const float* __restrict__ mask, float* __restrict__ aspect)
{
  int b = blockIdx.x, t = threadIdx.x;
  __shared__ float msk[NN_];
  __shared__ float wn;
  if (t < NN_) msk[t] = mask[b*NN_+t];
  __syncthreads();
  if (t==0){ float s=0.f; for (int n=0;n<NN_;++n) s+=msk[n]; wn=s; }
  __syncthreads();
  if (t < DM){
    float s=0.f;
    for (int n=0;n<NN_;++n) s += gin[((size_t)(b*NN_+n))*DM + t]*msk[n];
    aspect[b*DM+t] = s/wn;
  }
}

// ---------------- aw[b,h,e] = sum_d a[b,d] * weight_m[h,d,e] ----------------
__global__ __launch_bounds__(128) void aw_k(
    const float* __restrict__ a, const float* __restrict__ wm, float* __restrict__ aw)
{
  int b=blockIdx.x, h=blockIdx.y, e=threadIdx.x;
  if (e>=DKH) return;
  float s=0.f;
  for (int d=0; d<DKH; ++d) s += a[b*DKH+d]*wm[(h*DKH+d)*DKH+e];
  aw[(b*NH+h)*DKH+e]=s;
}

// ---------------- asc[b,h,m] = tanh(aw . k[b,h,m,:] + bias_m) ----------------
__global__ __launch_bounds__(128) void asc_k(
    const float* __restrict__ aw, const float* __restrict__ kp,
    const float* __restrict__ bias_m, float* __restrict__ asc)
{
  int b=blockIdx.x, h=blockIdx.y, m=threadIdx.x;
  __shared__ __align__(16) float awl[DKH];
  if (m<DKH) awl[m]=aw[(b*NH+h)*DKH+m];
  __syncthreads();
  const float* kr = kp + ((size_t)(b*NN_+m))*DM + h*DKH;
  const float4* a4=(const float4*)awl; const float4* k4=(const float4*)kr;
  float s=0.f;
#pragma unroll
  for (int e=0;e<DKH/4;e++){ float4 x=a4[e], y=k4[e]; s += x.x*y.x+x.y*y.y+x.z*y.z+x.w*y.w; }
  asc[(b*NH+h)*NN_+m] = tanhf(s + bias_m[0]);
}

// ---------------- scores + mask + short + softmax -> adj[B,H,N,N] ----------------
__global__ __launch_bounds__(128) void attn_k(
    const float* __restrict__ q, const float* __restrict__ kp,
    const float* __restrict__ asc, const float* __restrict__ shortm,
    const int* __restrict__ tok, float* __restrict__ adj)
{
  int n=blockIdx.x, h=blockIdx.y, b=blockIdx.z, m=threadIdx.x;
  __shared__ __align__(16) float qrow[DKH];
  __shared__ float red[NN_];
  if (m < DKH) qrow[m] = q[((size_t)(b*NN_+n))*DM + h*DKH + m];
  __syncthreads();
  const float* kr = kp + ((size_t)(b*NN_+m))*DM + h*DKH;
  const float4* q4=(const float4*)qrow; const float4* k4=(const float4*)kr;
  float s=0.f;
#pragma unroll
  for (int e=0;e<DKH/4;e++){ float4 x=q4[e], y=k4[e]; s += x.x*y.x+x.y*y.y+x.z*y.z+x.w*y.w; }
  s = s*0.1f + asc[(b*NH+h)*NN_+m];
  if (tok[b*NN_+m]==0) s = -1e9f;
  s += shortm[((size_t)(b*NN_+n))*NN_+m];
  red[m]=s; __syncthreads();
  for (int o=64;o;o>>=1){ if (m<o) red[m]=fmaxf(red[m],red[m+o]); __syncthreads(); }
  float mx = red[0]; __syncthreads();
  float e = __expf(s-mx);
  red[m]=e; __syncthreads();
  for (int o=64;o;o>>=1){ if (m<o) red[m]+=red[m+o]; __syncthreads(); }
  adj[(((size_t)b*NH+h)*NN_+n)*NN_+m] = e/red[0];
}

// ---------------- adjsum = sum_h adj / H; whs = sum_h adj*swx[h] / H ----------------
__global__ __launch_bounds__(256) void adjsum_k(
    const float* __restrict__ adj, const float* __restrict__ swx,
    float* __restrict__ adjs, float* __restrict__ whs)
{
  int idx = blockIdx.x*256 + threadIdx.x;
  int b = idx >> 14, rem = idx & 16383;
  float s=0.f, w=0.f;
  for (int h=0;h<NH;++h){
    float v = adj[(((size_t)b*NH+h)<<14) + rem];
    s += v; w += v*swx[h];
  }
  adjs[idx] = s*(1.f/NH);
  whs [idx] = w*(1.f/NH);
}

// ---------------- sg1[b,j]=g1.w1sum  sg2[b,j]=g1.w2sum ----------------
__global__ __launch_bounds__(128) void sg_k(
    const float* __restrict__ g1, const float* __restrict__ w1sum, const float* __restrict__ w2sum,
    float* __restrict__ sg1, float* __restrict__ sg2)
{
  int row = blockIdx.x*128 + threadIdx.x;
  const float* gr = g1 + (size_t)row*DM;
  float s1=0.f,s2=0.f;
  for (int d=0;d<DM;++d){ float g=gr[d]; s1+=g*w1sum[d]; s2+=g*w2sum[d]; }
  sg1[row]=s1; sg2[row]=s2;
}

// ---------------- adjsum2[b,i,j] = whs + (sg1[b,j]+sg2[b,i]+sbx)/H ----------------
__global__ __launch_bounds__(256) void adjsum2_k(
    const float* __restrict__ whs, const float* __restrict__ sg1, const float* __restrict__ sg2,
    const float* __restrict__ sbx, float* __restrict__ adjs)
{
  int idx = blockIdx.x*256 + threadIdx.x;
  int b = idx >> 14, rem = idx & 16383;
  int i = rem >> 7, j = rem & 127;
  adjs[idx] = whs[idx] + (sg1[b*NN_+j] + sg2[b*NN_+i] + sbx[0])*(1.f/NH);
}

// ---------------- pooled mean + logits ----------------
__global__ __launch_bounds__(320) void pooled_k(
    const float* __restrict__ hn, const float* __restrict__ mask,
    const float* __restrict__ Wc, const float* __restrict__ bc, float* __restrict__ out)
{
  int b=blockIdx.x, t=threadIdx.x;
  __shared__ float msk[NN_];
  __shared__ float pl[RHID];
  __shared__ float wn;
  if (t<NN_) msk[t]=mask[b*NN_+t];
  __syncthreads();
  if (t==0){ float s=0.f; for (int n=0;n<NN_;++n) s+=msk[n]; wn=s; }
  __syncthreads();
  if (t<RHID){
    float s=0.f;
    for (int n=0;n<NN_;++n) s += hn[((size_t)(b*NN_+n))*RHID+t]*msk[n];
    pl[t]=s/wn;
  }
  __syncthreads();
  if (t<3){
    float s=bc[t];
    for (int d=0;d<RHID;++d) s += pl[d]*Wc[t*RHID+d];
    out[b*3+t]=s;
  }
}

extern "C" void kernel_launch(void* const* d_in, const int* in_sizes, int n_in,
                              void* d_out, int out_size, void* d_ws, size_t ws_size,
                              hipStream_t stream)
{
  (void)in_sizes; (void)n_in; (void)out_size; (void)ws_size;
  const int*   tok      = (const int*)  d_in[0];
  const int*   pos_ids  = (const int*)  d_in[2];
  const int*   post_ids = (const int*)  d_in[5];
  const float* mask     = (const float*)d_in[6];
  const float* shortm   = (const float*)d_in[8];
  const float* emb_w    = (const float*)d_in[9];
  const float* pos_w    = (const float*)d_in[10];
  const float* post_w   = (const float*)d_in[11];
  const float* Wih_f    = (const float*)d_in[12];
  const float* Whh_f    = (const float*)d_in[13];
  const float* b_f      = (const float*)d_in[14];
  const float* Wih_b    = (const float*)d_in[15];
  const float* Whh_b    = (const float*)d_in[16];
  const float* b_b      = (const float*)d_in[17];
  const float* Wq       = (const float*)d_in[18];
  const float* bq       = (const float*)d_in[19];
  const float* Wk       = (const float*)d_in[20];
  const float* bk       = (const float*)d_in[21];
  const float* Wd       = (const float*)d_in[22];
  const float* bd       = (const float*)d_in[23];
  const float* weight_m = (const float*)d_in[24];
  const float* bias_m   = (const float*)d_in[25];
  const float* Ww       = (const float*)d_in[26];
  const float* bw       = (const float*)d_in[27];
  const float* Wx       = (const float*)d_in[28];
  const float* bx       = (const float*)d_in[29];
  const float* Wxx      = (const float*)d_in[30];
  const float* bxx      = (const float*)d_in[31];
  const float* Wc       = (const float*)d_in[32];
  const float* bc       = (const float*)d_in[33];

  float* ws  = (float*)d_ws;
  float* out = (float*)d_out;

  float* gin    = ws + OFF_GIN;
  float* embs   = ws + OFF_EMBS;
  float* wihpF  = ws + OFF_WIHPF;
  float* wihpB  = ws + OFF_WIHPB;
  float* bpF    = ws + OFF_BPF;
  float* bpB    = ws + OFF_BPB;
  float* aspect = ws + OFF_ASPECT;
  float* abuf   = ws + OFF_A;
  float* awb    = ws + OFF_AW;
  float* ascb   = ws + OFF_ASC;
  float* w1sum  = ws + OFF_W1SUM;
  float* w2sum  = ws + OFF_W2SUM;
  float* swx    = ws + OFF_SWX;
  float* sbx    = ws + OFF_SBX;
  float* sg1    = ws + OFF_SG1;
  float* sg2    = ws + OFF_SG2;
  float* xgf    = ws + OFF_XGF;
  float* xgb    = ws + OFF_XGB;
  __bf16* wtb   = (__bf16*)(ws + OFF_WTB);
  __bf16* hbuf  = (__bf16*)(ws + OFF_HBUF);
  int*   ctr    = (int*)(ws + OFF_CTR);
  float* qb     = ws + OFF_Q;
  float* kb     = ws + OFF_K;
  float* adjb   = ws + OFF_ADJ;
  float* adjs   = ws + OFF_ADJS;
  float* whs    = ws + OFF_WHS;
  float* axb    = ws + OFF_AX;
  float* g1b    = ws + OFF_G1;
  float* ax2b   = ws + OFF_AX2;
  float* g2b    = ws + OFF_G2;
  float* hnb    = ws + OFF_HN;

  // 1. embeddings + folded Wx constants + packing + init
  embed_k<<<dim3(BB*NN_),384,0,stream>>>(tok,pos_ids,post_ids,emb_w,pos_w,post_w,embs);
  consts_k<<<1,640,0,stream>>>(Wx,bx,w1sum,w2sum,swx,sbx);
  wihp_k<<<dim3((G4*INDIM+G4+255)/256),256,0,stream>>>(Wih_f,b_f,wihpF,bpF);
  wihp_k<<<dim3((G4*INDIM+G4+255)/256),256,0,stream>>>(Wih_b,b_b,wihpB,bpB);
  whhp_k<<<dim3((G4*KPAD+255)/256),256,0,stream>>>(Whh_f, wtb);
  whhp_k<<<dim3((G4*KPAD+255)/256),256,0,stream>>>(Whh_b, wtb + (size_t)G4*KPAD);
  init_k<<<dim3((40964+255)/256),256,0,stream>>>(ws + OFF_HBUF);
  // 2. LSTM input projections (gate-interleaved packed rows)
  gemm_k<false,0><<<dim3(10,64,1),256,0,stream>>>(embs,wihpF,bpF,xgf, BB*NN_,G4,INDIM, 0,0,0);
  gemm_k<false,0><<<dim3(10,64,1),256,0,stream>>>(embs,wihpB,bpB,xgb, BB*NN_,G4,INDIM, 0,0,0);
  // 3. recurrence: cooperative-cluster MFMA (50 co-resident blocks)
  lstm_mfma_k<<<dim3(2*S_CL),256,0,stream>>>(xgf,xgb,wtb,hbuf,ctr,gin);
  // 4. aspect mean, Q/K projections, aspect-bias path
  aspect_k<<<BB,640,0,stream>>>(gin,mask,aspect);
  gemm_k<false,0><<<dim3(5,64,1),256,0,stream>>>(gin,Wq,bq,qb, BB*NN_,DM,DM, 0,0,0);
  gemm_k<false,0><<<dim3(5,64,1),256,0,stream>>>(gin,Wk,bk,kb, BB*NN_,DM,DM, 0,0,0);
  gemm_k<false,0><<<dim3(1,1,1),256,0,stream>>>(aspect,Wd,bd,abuf, BB,DKH,DM, 0,0,0);
  aw_k <<<dim3(BB,NH),128,0,stream>>>(abuf,weight_m,awb);
  asc_k<<<dim3(BB,NH),128,0,stream>>>(awb,kb,bias_m,ascb);
  // 5. scores + softmax
  attn_k<<<dim3(NN_,NH,BB),128,0,stream>>>(qb,kb,ascb,shortm,tok,adjb);
  // 6. GCN layer 1
  adjsum_k<<<4096,256,0,stream>>>(adjb,swx,adjs,whs);
  gemm_k<true,0><<<dim3(5,1,64),256,0,stream>>>(adjs,gin,nullptr,axb, NN_,DM,NN_, 16384,76800,76800);
  gemm_k<false,1><<<dim3(5,64,1),256,0,stream>>>(axb,Ww,bw,g1b, BB*NN_,DM,DM, 0,0,0);
  // 7. layer-2 adjacency collapsed
  sg_k<<<64,128,0,stream>>>(g1b,w1sum,w2sum,sg1,sg2);
  adjsum2_k<<<4096,256,0,stream>>>(whs,sg1,sg2,sbx,adjs);
  // 8. GCN layer 2
  gemm_k<true,0><<<dim3(5,1,64),256,0,stream>>>(adjs,g1b,nullptr,ax2b, NN_,DM,NN_, 16384,76800,76800);
  gemm_k<false,1><<<dim3(5,64,1),256,0,stream>>>(ax2b,Ww,bw,g2b, BB*NN_,DM,DM, 0,0,0);
  // 9. head
  gemm_k<false,2><<<dim3(3,64,1),256,0,stream>>>(g2b,Wxx,bxx,hnb, BB*NN_,RHID,DM, 0,0,0);
  pooled_k<<<BB,320,0,stream>>>(hnb,mask,Wc,bc,out);
}

// Round 5
// 2647.669 us; speedup vs baseline: 2.1972x; 1.1477x over previous
//
#include <hip/hip_runtime.h>
#include <math.h>

// ---- problem constants ----
#define BB    64
#define NN_   128
#define NH    6
#define DM    600     // d_model
#define RHID  300     // rnn hidden
#define DKH   100     // per-head dim
#define INDIM 360
#define G4    1200    // 4*RHID
#define WXROW 1206    // NH + 2*DM
#define DMP   608     // DM padded to mult of 32
#define INP   384     // INDIM padded

// ---- LSTM cluster config ----
#define S_CL  25
#define NSU   12
#define NSR   48
#define KPAD  320

// ---- workspace layout (float offsets). Peak = 26,450,432 fl = 105.8 MB ----
#define OFF_GINB   0ull                 // bf16 [8192][608] = 2,490,368 fl
#define OFF_ASPECT 2490368ull           // fp32 [64][600]
#define OFF_ABUF   2528768ull           // fp32 [64][100]
#define OFF_AWB    2535168ull           // fp32 [64][6][100]
#define OFF_ASCB   2573568ull           // fp32 [64][6][128]
#define OFF_W1SUM  2622720ull
#define OFF_W2SUM  2623360ull
#define OFF_SWX    2624000ull
#define OFF_SBX    2624016ull
#define OFF_SG1    2624032ull
#define OFF_SG2    2632224ull
#define OFF_WHS    2640416ull           // fp32 [64][128][128] = 1,048,576
#define OFF_WQKP   3688992ull           // bf16 [1200][608] = 364,800 fl
#define OFF_BQK    4053792ull           // fp32 1200
#define OFF_WWP    4054992ull           // bf16 [600][608] = 182,400 fl
#define OFF_WXXP   4237392ull           // bf16 [300][608] = 91,200 fl
#define OFF_WIHPF  4328592ull           // bf16 [1200][384] = 230,400 fl
#define OFF_WIHPB  4558992ull
#define OFF_BPF    4789392ull
#define OFF_BPB    4790592ull
#define OFF_WTB    4791792ull           // bf16 [2][1200][320] = 384,000 fl
#define OFF_HBUF   5175792ull           // bf16 2*2*64*320 = 40,960 fl
#define OFF_CTR    5216752ull
#define OFF_EMBS   5216768ull           // bf16 [8192][384] = 1,572,864 fl
#define ARENA      6789632ull
#define OFF_XGF    (ARENA)              // fp32 9,830,400
#define OFF_XGB    (ARENA + 9830400ull) // fp32 9,830,400 -> peak 26,450,432
// post-lstm reuse:
#define OFF_QKB    (ARENA)                      // fp32 [8192][1200] (over xgf, dead)
#define OFF_ADJ    (ARENA + 9830400ull)         // fp32 [64][6][128][128] (over xgb)
#define OFF_ADJS   (ARENA + 16121856ull)        // bf16 [64][128][128] = 524,288 fl
#define OFF_GINT   (ARENA + 16646144ull)        // bf16 [64][608][128] = 2,490,368 fl
#define OFF_AXB    (ARENA)                      // bf16 2,490,368 fl (over qkb, dead after attn)
#define OFF_G1B    (ARENA + 2490368ull)         // bf16 2,490,368 fl
#define OFF_G1T    (OFF_GINT)                   // ginT dead after Ax1
#define OFF_AX2B   (ARENA + 4980736ull)         // bf16 2,490,368 fl
#define OFF_G2B    (ARENA + 7471104ull)         // bf16 2,490,368 fl
#define OFF_HNB    (ARENA + 9961472ull)         // fp32 [8192][300] (over adjb, dead)

typedef __bf16 bf16x8 __attribute__((ext_vector_type(8)));
typedef float  f32x4  __attribute__((ext_vector_type(4)));

__device__ __forceinline__ float sigm(float x){ return 1.f/(1.f+__expf(-x)); }
__device__ __forceinline__ float selu_f(float x){
  const float sc=1.0507009873554805f, al=1.6732632423543772f;
  return x>0.f ? sc*x : sc*al*(__expf(x)-1.f);
}
__device__ __forceinline__ bf16x8 bzero8(){
  bf16x8 z;
#pragma unroll
  for (int j=0;j<8;++j) z[j]=(__bf16)0.f;
  return z;
}

// ---------------- embedding concat -> bf16 [8192][384], pads written zero ----------------
__global__ __launch_bounds__(384) void embed_k(
    const int* __restrict__ tok, const int* __restrict__ pos_ids, const int* __restrict__ post_ids,
    const float* __restrict__ emb_w, const float* __restrict__ pos_w, const float* __restrict__ post_w,
    __bf16* __restrict__ embs)
{
  int bn = blockIdx.x, t = threadIdx.x;
  float v = 0.f;
  if      (t < 300) v = emb_w [(size_t)tok     [bn]*300 + t];
  else if (t < 330) v = pos_w [(size_t)pos_ids [bn]*30  + (t-300)];
  else if (t < 360) v = post_w[(size_t)post_ids[bn]*30  + (t-330)];
  embs[(size_t)bn*INP + t] = (__bf16)v;   // t in [360,384) -> 0
}

// ---------------- zero ginb pad cols [600,608) ----------------
__global__ __launch_bounds__(256) void gpad_k(__bf16* __restrict__ g)
{
  int idx = blockIdx.x*256 + threadIdx.x;   // < 65,536
  int row = idx >> 3, c = idx & 7;
  g[(size_t)row*DMP + DM + c] = (__bf16)0.f;
}

// ---------------- Wx folded constants ----------------
__global__ __launch_bounds__(640) void consts_k(
    const float* __restrict__ Wx, const float* __restrict__ bx,
    float* __restrict__ w1sum, float* __restrict__ w2sum,
    float* __restrict__ swx, float* __restrict__ sbx)
{
  int t = threadIdx.x;
  if (t < DM){
    float s1=0.f, s2=0.f;
    for (int k=0;k<NH;++k){ s1 += Wx[k*WXROW + NH + t]; s2 += Wx[k*WXROW + NH + DM + t]; }
    w1sum[t]=s1; w2sum[t]=s2;
  } else if (t < DM+NH){
    int h=t-DM; float s=0.f;
    for (int k=0;k<NH;++k) s += Wx[k*WXROW + h];
    swx[h]=s;
  } else if (t == DM+NH){
    float s=0.f; for (int k=0;k<NH;++k) s += bx[k];
    sbx[0]=s;
  }
}

// ---------------- pack Wih (gate-interleaved rows p=4u+g) -> bf16 [1200][384] ----------------
__global__ __launch_bounds__(256) void wihp_k(
    const float* __restrict__ Wih, const float* __restrict__ b,
    __bf16* __restrict__ wp, float* __restrict__ bp)
{
  int idx = blockIdx.x*256 + threadIdx.x;
  if (idx < G4*INP){
    int p = idx / INP, k = idx - p*INP;
    int srow = (p&3)*RHID + (p>>2);
    wp[idx] = (k<INDIM) ? (__bf16)Wih[(size_t)srow*INDIM + k] : (__bf16)0.f;
  } else if (idx < G4*INP + G4){
    int p = idx - G4*INP;
    bp[p] = b[(p&3)*RHID + (p>>2)];
  }
}

// ---------------- pack Wq||Wk -> bf16 [1200][608], bias ----------------
__global__ __launch_bounds__(256) void wqkp_k(
    const float* __restrict__ Wq, const float* __restrict__ bq,
    const float* __restrict__ Wk, const float* __restrict__ bk,
    __bf16* __restrict__ wp, float* __restrict__ bp)
{
  int idx = blockIdx.x*256 + threadIdx.x;
  if (idx < G4*DMP){
    int n = idx / DMP, k = idx - n*DMP;
    float v = 0.f;
    if (k < DM) v = (n < DM) ? Wq[(size_t)n*DM + k] : Wk[(size_t)(n-DM)*DM + k];
    wp[idx] = (__bf16)v;
  } else if (idx < G4*DMP + G4){
    int n = idx - G4*DMP;
    bp[n] = (n < DM) ? bq[n] : bk[n-DM];
  }
}

// ---------------- generic weight pack fp32[n][ksrc] -> bf16[n][kp] (k-pads zero) ----------------
__global__ __launch_bounds__(256) void wpk_k(
    const float* __restrict__ W, __bf16* __restrict__ wp, int nrows, int ksrc, int kp)
{
  int idx = blockIdx.x*256 + threadIdx.x;
  if (idx >= nrows*kp) return;
  int n = idx / kp, k = idx - n*kp;
  wp[idx] = (k < ksrc) ? (__bf16)W[(size_t)n*ksrc + k] : (__bf16)0.f;
}

// ---------------- pack Whh -> bf16 [p=4u+g][KPAD] ----------------
__global__ __launch_bounds__(256) void whhp_k(
    const float* __restrict__ Whh, __bf16* __restrict__ outW)
{
  int idx = blockIdx.x*256 + threadIdx.x;
  if (idx >= G4*KPAD) return;
  int p = idx / KPAD, k = idx - p*KPAD;
  outW[idx] = (k < RHID) ? (__bf16)Whh[((size_t)((p&3)*RHID + (p>>2)))*RHID + k] : (__bf16)0.f;
}

// ---------------- zero hbuf + cluster counters ----------------
__global__ __launch_bounds__(256) void init_k(float* __restrict__ z)
{
  int idx = blockIdx.x*256 + threadIdx.x;
  if (idx < 40964) z[idx] = 0.f;
}

// ---------------- LDS-free bf16 MFMA GEMM: C = act(A @ B^T + bias) ----------------
// Per wave: 16 A-rows VGPR-resident as fragments; loop 16-col n-tiles; B streamed from L2.
// Fragment/D layouts identical to the R3-hardware-validated lstm_mfma pattern.
// A [M,K] bf16 (lda=K), B [N,K] bf16; K = KT*32; M multiple of 64 per grid.
template<int KT, int ACT, int OBF>
__global__ __launch_bounds__(256) void wgemm_k(
    const __bf16* __restrict__ A, const __bf16* __restrict__ B,
    const float* __restrict__ bias, void* __restrict__ Cout,
    int Nn, int Npad, int ldc,
    long long sA, long long sB, long long sC)
{
  const int tid = threadIdx.x, lane = tid & 63, wave = tid >> 6;
  const int fn = lane & 15, fq = lane >> 4;
  const int K = KT*32;
  const __bf16* Ab = A + (size_t)blockIdx.z * (size_t)sA;
  const __bf16* Bb = B + (size_t)blockIdx.z * (size_t)sB;
  float*  Cf = (float*) Cout + (size_t)blockIdx.z * (size_t)sC;
  __bf16* Ch = (__bf16*)Cout + (size_t)blockIdx.z * (size_t)sC;

  const int m0 = (blockIdx.x*4 + wave)*16;

  // A-fragments for this wave's 16 rows, VGPR-resident (KT*4 VGPRs)
  bf16x8 Af[KT];
#pragma unroll
  for (int kt=0; kt<KT; ++kt)
    Af[kt] = *(const bf16x8*)(Ab + (size_t)(m0 + fn)*K + kt*32 + fq*8);

  for (int n0 = blockIdx.y*16; n0 < Nn; n0 += 16*gridDim.y){
    const int gn = n0 + fn;
    const int gnc = (gn < Nn) ? gn : 0;       // clamp address (stay in-bounds)
    f32x4 acc = {0.f,0.f,0.f,0.f};
#pragma unroll
    for (int kt=0; kt<KT; ++kt){
      bf16x8 Bf = *(const bf16x8*)(Bb + (size_t)gnc*K + kt*32 + fq*8);
      if (gn >= Nn) Bf = bzero8();            // per-lane select; exec stays uniform for MFMA
      acc = __builtin_amdgcn_mfma_f32_16x16x32_bf16(Af[kt], Bf, acc, 0, 0, 0);
    }
    float bv = (bias && gn < Nn) ? bias[gn] : 0.f;
#pragma unroll
    for (int r=0; r<4; ++r){
      int gm = m0 + fq*4 + r;
      float v = acc[r] + bv;
      if (ACT==1) v = selu_f(v);
      else if (ACT==2) v = fmaxf(v, 0.f);
      if (gn < Nn){
        if (OBF) Ch[(size_t)gm*ldc + gn] = (__bf16)v;
        else     Cf[(size_t)gm*ldc + gn] = v;
      } else if (gn < Npad){
        if (OBF) Ch[(size_t)gm*ldc + gn] = (__bf16)0.f;
        else     Cf[(size_t)gm*ldc + gn] = 0.f;
      }
    }
  }
}

// ---------------- legacy fp32 GEMM (only for tiny aspect@Wd) ----------------
template<bool TRANSB, int ACT>
__global__ __launch_bounds__(256) void gemm_k(
    const float* __restrict__ A, const float* __restrict__ Bm,
    const float* __restrict__ bias, float* __restrict__ C,
    int M, int Nn, int K, long long sA, long long sB, long long sC)
{
  __shared__ __align__(16) float As[16][132];
  __shared__ __align__(16) float Bs[16][132];
  const float* Ab = A  + (size_t)blockIdx.z * (size_t)sA;
  const float* Bb = Bm + (size_t)blockIdx.z * (size_t)sB;
  float*       Cb = C  + (size_t)blockIdx.z * (size_t)sC;
  const int m0 = blockIdx.y * 128, n0 = blockIdx.x * 128;
  const int lin = threadIdx.x;
  const int tx = lin & 15, ty = lin >> 4;
  float acc[8][8];
#pragma unroll
  for (int i=0;i<8;i++)
#pragma unroll
    for (int j=0;j<8;j++) acc[i][j]=0.f;
  for (int k0=0; k0<K; k0+=16) {
#pragma unroll
    for (int r=0;r<2;++r){
      int e = lin*2+r;
      int row = e>>2, kq=(e&3)*4;
      float4 v = make_float4(0.f,0.f,0.f,0.f);
      int gm=m0+row, gk=k0+kq;
      if (gm<M && gk<K) v = *(const float4*)(Ab + (size_t)gm*K + gk);
      As[kq+0][row]=v.x; As[kq+1][row]=v.y; As[kq+2][row]=v.z; As[kq+3][row]=v.w;
    }
#pragma unroll
    for (int r=0;r<2;++r){
      int e = lin*2+r;
      int col = e>>2, kq=(e&3)*4;
      float4 v = make_float4(0.f,0.f,0.f,0.f);
      int gn=n0+col, gk=k0+kq;
      if (gn<Nn && gk<K) v = *(const float4*)(Bb + (size_t)gn*K + gk);
      Bs[kq+0][col]=v.x; Bs[kq+1][col]=v.y; Bs[kq+2][col]=v.z; Bs[kq+3][col]=v.w;
    }
    __syncthreads();
#pragma unroll
    for (int kk=0;kk<16;++kk){
      float a[8], bv[8];
      *(float4*)&a[0]  = *(const float4*)&As[kk][ty*8];
      *(float4*)&a[4]  = *(const float4*)&As[kk][ty*8+4];
      *(float4*)&bv[0] = *(const float4*)&Bs[kk][tx*8];
      *(float4*)&bv[4] = *(const float4*)&Bs[kk][tx*8+4];
#pragma unroll
      for (int i=0;i<8;i++)
#pragma unroll
        for (int j=0;j<8;j++) acc[i][j] = fmaf(a[i], bv[j], acc[i][j]);
    }
    __syncthreads();
  }
#pragma unroll
  for (int i=0;i<8;i++){
    int gm = m0 + ty*8 + i;
    if (gm>=M) continue;
#pragma unroll
    for (int j=0;j<8;j+=4){
      int gn = n0 + tx*8 + j;
      if (gn>=Nn) continue;
      float t0=acc[i][j+0], t1=acc[i][j+1], t2=acc[i][j+2], t3=acc[i][j+3];
      if (bias){ t0+=bias[gn]; t1+=bias[gn+1]; t2+=bias[gn+2]; t3+=bias[gn+3]; }
      float4 v; v.x=t0; v.y=t1; v.z=t2; v.w=t3;
      *(float4*)(Cb + (size_t)gm*Nn + gn) = v;
    }
  }
}

// ---------------- bf16 per-batch transpose [64][128][608] -> [64][608][128] ----------------
__global__ __launch_bounds__(256) void tr_k(
    const __bf16* __restrict__ in, __bf16* __restrict__ out)
{
  const int b = blockIdx.z, m0 = blockIdx.y*64, d0 = blockIdx.x*64;
  const int tid = threadIdx.x;
  __shared__ __align__(16) __bf16 T[64][72];
  const __bf16* ib = in + (size_t)b*NN_*DMP;
  __bf16* ob = out + (size_t)b*DMP*NN_;
#pragma unroll
  for (int r=0;r<2;++r){
    int idx = tid + 256*r;
    int mi = idx>>3, ch = idx&7;
    int d = d0 + ch*8;
    bf16x8 v = bzero8();
    if (d < DMP) v = *(const bf16x8*)(ib + (size_t)(m0+mi)*DMP + d);
    *(bf16x8*)&T[mi][ch*8] = v;
  }
  __syncthreads();
#pragma unroll
  for (int r=0;r<2;++r){
    int idx = tid + 256*r;
    int di = idx>>3, mch = idx&7;
    int d = d0 + di;
    if (d >= DMP) continue;
    bf16x8 v;
#pragma unroll
    for (int j=0;j<8;++j) v[j] = T[mch*8+j][di];
    *(bf16x8*)(ob + (size_t)d*NN_ + m0 + mch*8) = v;
  }
}

// ---------------- cooperative-cluster MFMA LSTM (R3-validated body; bf16 gin out) ----------------
__global__ __launch_bounds__(256, 1) void lstm_mfma_k(
    const float* __restrict__ xgf, const float* __restrict__ xgb,
    const __bf16* __restrict__ wtb,
    __bf16* hbuf, int* ctr,
    __bf16* __restrict__ ginb)
{
  const int blk = blockIdx.x;
  const int dir = blk / S_CL, sl = blk - dir*S_CL;
  const int tid = threadIdx.x, lane = tid & 63, wave = tid >> 6;
  const int p0 = sl * NSR;
  const float* xg = dir ? xgb : xgf;
  const __bf16* W = wtb + (size_t)dir * G4 * KPAD;
  __bf16* hb = hbuf + (size_t)dir * 2 * BB * KPAD;
  int* c_ctr = ctr + dir;

  __shared__ __align__(16) float accS[NSR][68];

  const int fn = lane & 15;
  const int fk = (lane >> 4) * 8;
  const int m0 = wave * 16;

  bf16x8 Bf[3][10];
#pragma unroll
  for (int nt = 0; nt < 3; ++nt)
#pragma unroll
    for (int kt = 0; kt < 10; ++kt)
      Bf[nt][kt] = *(const bf16x8*)(W + (size_t)(p0 + nt*16 + fn)*KPAD + kt*32 + fk);

  int ib[3], iu[3]; float cst[3];
#pragma unroll
  for (int j = 0; j < 3; ++j){
    int item = tid + 256*j;
    iu[j] = item % NSU; ib[j] = item / NSU;
    cst[j] = 0.f;
  }

  for (int s = 0; s < NN_; ++s){
    const int n_t = dir ? (NN_-1-s) : s;
    const __bf16* hbr = hb + ((s+1)&1) * (BB*KPAD);
    __bf16*       hbw = hb + ( s   &1) * (BB*KPAD);

    bf16x8 Af[10];
#pragma unroll
    for (int kt = 0; kt < 10; ++kt)
      Af[kt] = *(const bf16x8*)(hbr + (size_t)(m0 + fn)*KPAD + kt*32 + fk);

    f32x4 acc[3] = { {0.f,0.f,0.f,0.f}, {0.f,0.f,0.f,0.f}, {0.f,0.f,0.f,0.f} };
#pragma unroll
    for (int kt = 0; kt < 10; ++kt)
#pragma unroll
      for (int nt = 0; nt < 3; ++nt)
        acc[nt] = __builtin_amdgcn_mfma_f32_16x16x32_bf16(Af[kt], Bf[nt][kt], acc[nt], 0, 0, 0);

#pragma unroll
    for (int nt = 0; nt < 3; ++nt)
      *(f32x4*)&accS[nt*16 + fn][m0 + (lane>>4)*4] = acc[nt];
    __syncthreads();

#pragma unroll
    for (int j = 0; j < 3; ++j){
      int u = iu[j], b = ib[j];
      const float* xr = xg + ((size_t)(b*NN_ + n_t))*G4 + p0 + u*4;
      float4 x4 = *(const float4*)xr;
      float p_i = accS[u*4+0][b] + x4.x;
      float p_f = accS[u*4+1][b] + x4.y;
      float p_g = accS[u*4+2][b] + x4.z;
      float p_o = accS[u*4+3][b] + x4.w;
      float ig = sigm(p_i), fg = sigm(p_f), gg = tanhf(p_g), og = sigm(p_o);
      float c = fg*cst[j] + ig*gg; cst[j] = c;
      float h = og * tanhf(c);
      int u_glob = sl*NSU + u;
      hbw[(size_t)b*KPAD + u_glob] = (__bf16)h;
      ginb[((size_t)(b*NN_ + n_t))*DMP + dir*RHID + u_glob] = (__bf16)h;
    }
    __threadfence();
    __syncthreads();
    if (tid == 0){
      __hip_atomic_fetch_add(c_ctr, 1, __ATOMIC_RELEASE, __HIP_MEMORY_SCOPE_AGENT);
      const int target = S_CL * (s+1);
      while (__hip_atomic_load(c_ctr, __ATOMIC_ACQUIRE, __HIP_MEMORY_SCOPE_AGENT) < target)
        __builtin_amdgcn_s_sleep(2);
    }
    __syncthreads();
  }
}

// ---------------- masked mean over sequence -> aspect[B,DM] (bf16 in) ----------------
__global__ __launch_bounds__(640) void aspect_k(
    const __bf16* __restrict__ ginb, const float* __restrict__ mask, float* __restrict__ aspect)
{
  int b = blockIdx.x, t = threadIdx.x;
  __shared__ float msk[NN_];
  __shared__ float wn;
  if (t < NN_) msk[t] = mask[b*NN_+t];
  __syncthreads();
  if (t==0){ float s=0.f; for (int n=0;n<NN_;++n) s+=msk[n]; wn=s; }
  __syncthreads();
  if (t < DM){
    float s=0.f;
    for (int n=0;n<NN_;++n) s += (float)ginb[((size_t)(b*NN_+n))*DMP + t]*msk[n];
    aspect[b*DM+t] = s/wn;
  }
}

// ---------------- aw[b,h,e] = sum_d a[b,d] * weight_m[h,d,e] ----------------
__global__ __launch_bounds__(128) void aw_k(
    const float* __restrict__ a, const float* __restrict__ wm, float* __restrict__ aw)
{
  int b=blockIdx.x, h=blockIdx.y, e=threadIdx.x;
  if (e>=DKH) return;
  float s=0.f;
  for (int d=0; d<DKH; ++d) s += a[b*DKH+d]*wm[(h*DKH+d)*DKH+e];
  aw[(b*NH+h)*DKH+e]=s;
}

// ---------------- asc[b,h,m] = tanh(aw . k[b,h,m,:] + bias_m) (k inside qkb) ----------------
__global__ __launch_bounds__(128) void asc_k(
    const float* __restrict__ aw, const float* __restrict__ qkb,
    const float* __restrict__ bias_m, float* __restrict__ asc)
{
  int b=blockIdx.x, h=blockIdx.y, m=threadIdx.x;
  __shared__ __align__(16) float awl[DKH];
  if (m<DKH) awl[m]=aw[(b*NH+h)*DKH+m];
  __syncthreads();
  const float* kr = qkb + ((size_t)(b*NN_+m))*G4 + DM + h*DKH;
  const float4* a4=(const float4*)awl; const float4* k4=(const float4*)kr;
  float s=0.f;
#pragma unroll
  for (int e=0;e<DKH/4;e++){ float4 x=a4[e], y=k4[e]; s += x.x*y.x+x.y*y.y+x.z*y.z+x.w*y.w; }
  asc[(b*NH+h)*NN_+m] = tanhf(s + bias_m[0]);
}

// ---------------- scores + mask + short + softmax -> adj[B,H,N,N] ----------------
__global__ __launch_bounds__(128) void attn_k(
    const float* __restrict__ qkb, const float* __restrict__ asc,
    const float* __restrict__ shortm, const int* __restrict__ tok, float* __restrict__ adj)
{
  int n=blockIdx.x, h=blockIdx.y, b=blockIdx.z, m=threadIdx.x;
  __shared__ __align__(16) float qrow[DKH];
  __shared__ float red[NN_];
  if (m < DKH) qrow[m] = qkb[((size_t)(b*NN_+n))*G4 + h*DKH + m];
  __syncthreads();
  const float* kr = qkb + ((size_t)(b*NN_+m))*G4 + DM + h*DKH;
  const float4* q4=(const float4*)qrow; const float4* k4=(const float4*)kr;
  float s=0.f;
#pragma unroll
  for (int e=0;e<DKH/4;e++){ float4 x=q4[e], y=k4[e]; s += x.x*y.x+x.y*y.y+x.z*y.z+x.w*y.w; }
  s = s*0.1f + asc[(b*NH+h)*NN_+m];
  if (tok[b*NN_+m]==0) s = -1e9f;
  s += shortm[((size_t)(b*NN_+n))*NN_+m];
  red[m]=s; __syncthreads();
  for (int o=64;o;o>>=1){ if (m<o) red[m]=fmaxf(red[m],red[m+o]); __syncthreads(); }
  float mx = red[0]; __syncthreads();
  float e = __expf(s-mx);
  red[m]=e; __syncthreads();
  for (int o=64;o;o>>=1){ if (m<o) red[m]+=red[m+o]; __syncthreads(); }
  adj[(((size_t)b*NH+h)*NN_+n)*NN_+m] = e/red[0];
}

// ---------------- adjsum -> bf16 adjs (/H) + fp32 whs ----------------
__global__ __launch_bounds__(256) void adjsum_k(
    const float* __restrict__ adj, const float* __restrict__ swx,
    __bf16* __restrict__ adjs, float* __restrict__ whs)
{
  int idx = blockIdx.x*256 + threadIdx.x;
  int b = idx >> 14, rem = idx & 16383;
  float s=0.f, w=0.f;
  for (int h=0;h<NH;++h){
    float v = adj[(((size_t)b*NH+h)<<14) + rem];
    s += v; w += v*swx[h];
  }
  adjs[idx] = (__bf16)(s*(1.f/NH));
  whs [idx] = w*(1.f/NH);
}

// ---------------- sg1/sg2 from g1 (bf16) ----------------
__global__ __launch_bounds__(128) void sg_k(
    const __bf16* __restrict__ g1, const float* __restrict__ w1sum, const float* __restrict__ w2sum,
    float* __restrict__ sg1, float* __restrict__ sg2)
{
  int row = blockIdx.x*128 + threadIdx.x;
  const __bf16* gr = g1 + (size_t)row*DMP;
  float s1=0.f,s2=0.f;
  for (int d=0;d<DM;++d){ float g=(float)gr[d]; s1+=g*w1sum[d]; s2+=g*w2sum[d]; }
  sg1[row]=s1; sg2[row]=s2;
}

// ---------------- adjs2[b,i,j] = whs + (sg1[b,j]+sg2[b,i]+sbx)/H -> bf16 ----------------
__global__ __launch_bounds__(256) void adjsum2_k(
    const float* __restrict__ whs, const float* __restrict__ sg1, const float* __restrict__ sg2,
    const float* __restrict__ sbx, __bf16* __restrict__ adjs)
{
  int idx = blockIdx.x*256 + threadIdx.x;
  int b = idx >> 14, rem = idx & 16383;
  int i = rem >> 7, j = rem & 127;
  adjs[idx] = (__bf16)(whs[idx] + (sg1[b*NN_+j] + sg2[b*NN_+i] + sbx[0])*(1.f/NH));
}

// ---------------- pooled mean + logits ----------------
__global__ __launch_bounds__(320) void pooled_k(
    const float* __restrict__ hn, const float* __restrict__ mask,
    const float* __restrict__ Wc, const float* __restrict__ bc, float* __restrict__ out)
{
  int b=blockIdx.x, t=threadIdx.x;
  __shared__ float msk[NN_];
  __shared__ float pl[RHID];
  __shared__ float wn;
  if (t<NN_) msk[t]=mask[b*NN_+t];
  __syncthreads();
  if (t==0){ float s=0.f; for (int n=0;n<NN_;++n) s+=msk[n]; wn=s; }
  __syncthreads();
  if (t<RHID){
    float s=0.f;
    for (int n=0;n<NN_;++n) s += hn[((size_t)(b*NN_+n))*RHID+t]*msk[n];
    pl[t]=s/wn;
  }
  __syncthreads();
  if (t<3){
    float s=bc[t];
    for (int d=0;d<RHID;++d) s += pl[d]*Wc[t*RHID+d];
    out[b*3+t]=s;
  }
}

extern "C" void kernel_launch(void* const* d_in, const int* in_sizes, int n_in,
                              void* d_out, int out_size, void* d_ws, size_t ws_size,
                              hipStream_t stream)
{
  (void)in_sizes; (void)n_in; (void)out_size; (void)ws_size;
  const int*   tok      = (const int*)  d_in[0];
  const int*   pos_ids  = (const int*)  d_in[2];
  const int*   post_ids = (const int*)  d_in[5];
  const float* mask     = (const float*)d_in[6];
  const float* shortm   = (const float*)d_in[8];
  const float* emb_w    = (const float*)d_in[9];
  const float* pos_w    = (const float*)d_in[10];
  const float* post_w   = (const float*)d_in[11];
  const float* Wih_f    = (const float*)d_in[12];
  const float* Whh_f    = (const float*)d_in[13];
  const float* b_f      = (const float*)d_in[14];
  const float* Wih_b    = (const float*)d_in[15];
  const float* Whh_b    = (const float*)d_in[16];
  const float* b_b      = (const float*)d_in[17];
  const float* Wq       = (const float*)d_in[18];
  const float* bq       = (const float*)d_in[19];
  const float* Wk       = (const float*)d_in[20];
  const float* bk       = (const float*)d_in[21];
  const float* Wd       = (const float*)d_in[22];
  const float* bd       = (const float*)d_in[23];
  const float* weight_m = (const float*)d_in[24];
  const float* bias_m   = (const float*)d_in[25];
  const float* Ww       = (const float*)d_in[26];
  const float* bw       = (const float*)d_in[27];
  const float* Wx       = (const float*)d_in[28];
  const float* bx       = (const float*)d_in[29];
  const float* Wxx      = (const float*)d_in[30];
  const float* bxx      = (const float*)d_in[31];
  const float* Wc       = (const float*)d_in[32];
  const float* bc       = (const float*)d_in[33];

  float* ws  = (float*)d_ws;
  float* out = (float*)d_out;

  __bf16* ginb  = (__bf16*)(ws + OFF_GINB);
  float* aspect = ws + OFF_ASPECT;
  float* abuf   = ws + OFF_ABUF;
  float* awb    = ws + OFF_AWB;
  float* ascb   = ws + OFF_ASCB;
  float* w1sum  = ws + OFF_W1SUM;
  float* w2sum  = ws + OFF_W2SUM;
  float* swx    = ws + OFF_SWX;
  float* sbx    = ws + OFF_SBX;
  float* sg1    = ws + OFF_SG1;
  float* sg2    = ws + OFF_SG2;
  float* whs    = ws + OFF_WHS;
  __bf16* wqkp  = (__bf16*)(ws + OFF_WQKP);
  float* bqk    = ws + OFF_BQK;
  __bf16* wwp   = (__bf16*)(ws + OFF_WWP);
  __bf16* wxxp  = (__bf16*)(ws + OFF_WXXP);
  __bf16* wihpF = (__bf16*)(ws + OFF_WIHPF);
  __bf16* wihpB = (__bf16*)(ws + OFF_WIHPB);
  float* bpF    = ws + OFF_BPF;
  float* bpB    = ws + OFF_BPB;
  __bf16* wtb   = (__bf16*)(ws + OFF_WTB);
  __bf16* hbuf  = (__bf16*)(ws + OFF_HBUF);
  int*   ctr    = (int*)(ws + OFF_CTR);
  __bf16* embs  = (__bf16*)(ws + OFF_EMBS);
  float* xgf    = ws + OFF_XGF;
  float* xgb    = ws + OFF_XGB;
  float* qkb    = ws + OFF_QKB;
  float* adjb   = ws + OFF_ADJ;
  __bf16* adjs  = (__bf16*)(ws + OFF_ADJS);
  __bf16* gint  = (__bf16*)(ws + OFF_GINT);
  __bf16* axb   = (__bf16*)(ws + OFF_AXB);
  __bf16* g1b   = (__bf16*)(ws + OFF_G1B);
  __bf16* g1t   = (__bf16*)(ws + OFF_G1T);
  __bf16* ax2b  = (__bf16*)(ws + OFF_AX2B);
  __bf16* g2b   = (__bf16*)(ws + OFF_G2B);
  float* hnb    = ws + OFF_HNB;

  // 1. embeddings, constants, weight packing, init
  embed_k<<<dim3(BB*NN_),384,0,stream>>>(tok,pos_ids,post_ids,emb_w,pos_w,post_w,embs);
  consts_k<<<1,640,0,stream>>>(Wx,bx,w1sum,w2sum,swx,sbx);
  wihp_k<<<dim3((G4*INP+G4+255)/256),256,0,stream>>>(Wih_f,b_f,wihpF,bpF);
  wihp_k<<<dim3((G4*INP+G4+255)/256),256,0,stream>>>(Wih_b,b_b,wihpB,bpB);
  wqkp_k<<<dim3((G4*DMP+G4+255)/256),256,0,stream>>>(Wq,bq,Wk,bk,wqkp,bqk);
  wpk_k<<<dim3((DM*DMP+255)/256),256,0,stream>>>(Ww,wwp,DM,DM,DMP);
  wpk_k<<<dim3((RHID*DMP+255)/256),256,0,stream>>>(Wxx,wxxp,RHID,DM,DMP);
  whhp_k<<<dim3((G4*KPAD+255)/256),256,0,stream>>>(Whh_f, wtb);
  whhp_k<<<dim3((G4*KPAD+255)/256),256,0,stream>>>(Whh_b, wtb + (size_t)G4*KPAD);
  init_k<<<dim3((40964+255)/256),256,0,stream>>>(ws + OFF_HBUF);
  // 2. LSTM input projections (bf16 MFMA, LDS-free), fp32 out
  wgemm_k<12,0,0><<<dim3(128,4,1),256,0,stream>>>(embs,wihpF,bpF,xgf, G4,G4,G4, 0,0,0);
  wgemm_k<12,0,0><<<dim3(128,4,1),256,0,stream>>>(embs,wihpB,bpB,xgb, G4,G4,G4, 0,0,0);
  // 3. recurrence (cooperative cluster), gin bf16 out; then zero gin pad cols
  lstm_mfma_k<<<dim3(2*S_CL),256,0,stream>>>(xgf,xgb,wtb,hbuf,ctr,ginb);
  gpad_k<<<dim3(256),256,0,stream>>>(ginb);
  // 4. fused Q||K projection, aspect path
  wgemm_k<19,0,0><<<dim3(128,4,1),256,0,stream>>>(ginb,wqkp,bqk,qkb, G4,G4,G4, 0,0,0);
  aspect_k<<<BB,640,0,stream>>>(ginb,mask,aspect);
  gemm_k<false,0><<<dim3(1,1,1),256,0,stream>>>(aspect,Wd,bd,abuf, BB,DKH,DM, 0,0,0);
  aw_k <<<dim3(BB,NH),128,0,stream>>>(abuf,weight_m,awb);
  asc_k<<<dim3(BB,NH),128,0,stream>>>(awb,qkb,bias_m,ascb);
  // 5. scores + softmax
  attn_k<<<dim3(NN_,NH,BB),128,0,stream>>>(qkb,ascb,shortm,tok,adjb);
  // 6. GCN layer 1 (bf16 MFMA)
  adjsum_k<<<4096,256,0,stream>>>(adjb,swx,adjs,whs);
  tr_k<<<dim3(10,2,BB),256,0,stream>>>(ginb,gint);
  wgemm_k<4,0,1><<<dim3(2,4,BB),256,0,stream>>>(adjs,gint,nullptr,axb, DM,DMP,DMP, 16384,(long long)DMP*NN_,(long long)NN_*DMP);
  wgemm_k<19,1,1><<<dim3(128,4,1),256,0,stream>>>(axb,wwp,bw,g1b, DM,DMP,DMP, 0,0,0);
  // 7. layer-2 adjacency collapsed
  sg_k<<<64,128,0,stream>>>(g1b,w1sum,w2sum,sg1,sg2);
  adjsum2_k<<<4096,256,0,stream>>>(whs,sg1,sg2,sbx,adjs);
  // 8. GCN layer 2
  tr_k<<<dim3(10,2,BB),256,0,stream>>>(g1b,g1t);
  wgemm_k<4,0,1><<<dim3(2,4,BB),256,0,stream>>>(adjs,g1t,nullptr,ax2b, DM,DMP,DMP, 16384,(long long)DMP*NN_,(long long)NN_*DMP);
  wgemm_k<19,1,1><<<dim3(128,4,1),256,0,stream>>>(ax2b,wwp,bw,g2b, DM,DMP,DMP, 0,0,0);
  // 9. head
  wgemm_k<19,2,0><<<dim3(128,4,1),256,0,stream>>>(g2b,wxxp,bxx,hnb, RHID,RHID,RHID, 0,0,0);
  pooled_k<<<BB,320,0,stream>>>(hnb,mask,Wc,bc,out);
}